// Round 1
// baseline (376.258 us; speedup 1.0000x reference)
//
#include <hip/hip_runtime.h>

// LinearFlexQMixer MI355X — round 9: LDS overlay -> 3 blocks/CU.
// R8 counters: MfmaUtil 8.2%, VALUBusy 23%, Occupancy 19.4%, HBM 4% -> pure
// latency-starvation at 2 blocks/CU (LDS-capped: 60KB/block). sattn and sout
// are only live strictly after barriers B2/B3, when the per-wave transpose
// slices are dead (last slice read aw2 is pre-B2; next write is post-next-B1).
// Alias them onto sSlice: 61,184 -> 52,480 B -> 3 blocks/CU, launch_bounds
// (256,3). Everything else unchanged from R8.

#define NA 16
#define NEn 128
#define EDm 96
#define ST 136  // LDS row stride (shorts); 272B rows -> <=2-way conflicts

typedef __attribute__((ext_vector_type(8))) short bf16x8;
typedef __attribute__((ext_vector_type(4))) float f32x4;

#define MFMA(a, b, c) __builtin_amdgcn_mfma_f32_16x16x32_bf16((a), (b), (c), 0, 0, 0)
#define LGKM0() __asm__ volatile("s_waitcnt lgkmcnt(0)" ::: "memory")

// d_ws layout (bf16 elems), per hypernet p at p*HYPE:
#define OFF_W1 0       // [nt8][kt3][64][8]  B-frags Phase A (fc1w)
#define OFF_WQ 12288   // [nt8][kt4][64][8]  B-frags Q (inw cols 0:128, pre-scaled)
#define OFF_WK 28672   // [h4][nt8][64][8]   B-frags qW (Wk^T per head, K=32)
#define OFF_WV 45056   // [h4][mt2][kt4][64][8] A-frags V^T (Wv^T per head)
#define OFF_WO 61440   // [nt8][kt4][64][8]  B-frags OUT (outw)
#define OFF_W2 77824   // [nt2][kt4][64][8]  B-frags X3 (fc2w)
#define HYPE 81920
#define WS_FLAG_OFF 327680  // int flag: mask dtype (1 => int32)

__device__ __forceinline__ unsigned short f2bf(float f) {
  unsigned u = __float_as_uint(f);
  u += 0x7fffu + ((u >> 16) & 1u);  // RNE
  return (unsigned short)(u >> 16);
}

// Store one 16x16 C-tile column (4 f32, rows row0+0..3, col) as bf16 into
// LDS row-major [..][ST]. Pairs lanes (col, col^1) via shfl so every dword
// is written by exactly one lane. Full-wave calls only.
__device__ __forceinline__ void ctile_store(unsigned short* dst, int row0,
                                            int col, f32x4 v) {
  unsigned short m0 = f2bf(v[0]), m1 = f2bf(v[1]), m2 = f2bf(v[2]),
                 m3 = f2bf(v[3]);
  unsigned x = (unsigned)m0 | ((unsigned)m1 << 16);
  unsigned y = (unsigned)m2 | ((unsigned)m3 << 16);
  unsigned ox = (unsigned)__shfl_xor((int)x, 1);
  unsigned oy = (unsigned)__shfl_xor((int)y, 1);
  unsigned w0, w1;
  int ra;
  if ((threadIdx.x & 1) == 0) {
    ra = 0;
    w0 = (x & 0xffffu) | (ox << 16);
    w1 = (x >> 16) | (ox & 0xffff0000u);
  } else {
    ra = 2;
    w0 = (oy & 0xffffu) | (y << 16);
    w1 = (oy >> 16) | (y & 0xffff0000u);
  }
  *(unsigned*)(dst + (row0 + ra) * ST + (col & ~1)) = w0;
  *(unsigned*)(dst + (row0 + ra + 1) * ST + (col & ~1)) = w1;
}

// ---- prep: 160 work blocks (one float4/thread, source-order) + 1 mask blk
__global__ void prep_kernel(const float* __restrict__ w_fc1w,
                            const float* __restrict__ w_inw,
                            const float* __restrict__ w_outw,
                            const float* __restrict__ w_fc2w,
                            const float* __restrict__ v_fc1w,
                            const float* __restrict__ v_inw,
                            const float* __restrict__ v_outw,
                            const float* __restrict__ v_fc2w,
                            const unsigned char* __restrict__ mask,
                            unsigned short* __restrict__ ws,
                            int* __restrict__ flag) {
  if (blockIdx.x == 160) {
    const uint4 v = *(const uint4*)(mask + threadIdx.x * 16);
    const unsigned nz = (v.x | v.y | v.z | v.w) & 0xffffff00u;
    const int any = __syncthreads_or((int)(nz != 0));
    if (threadIdx.x == 0) *flag = (any == 0) ? 1 : 0;
    return;
  }
  const int g = blockIdx.x * 256 + threadIdx.x;  // 0 .. 40959
  const int p = (g >= 20480) ? 1 : 0;
  const int off = (g - p * 20480) * 4;
  const float* fc1w = p ? v_fc1w : w_fc1w;
  const float* inw = p ? v_inw : w_inw;
  const float* outw = p ? v_outw : w_outw;
  const float* fc2w = p ? v_fc2w : w_fc2w;
  unsigned short* wsp = ws + p * HYPE;

  float4 v4;
  if (off < OFF_WQ) {
    v4 = *(const float4*)(fc1w + off);
#pragma unroll
    for (int r = 0; r < 4; ++r) {
      const int oe = off + r;
      const int k = oe >> 7, n = oe & 127;
      const int kt = k >> 5, kr = k & 31, j = kr & 7, khi = kr >> 3;
      const int nt = n >> 4, lo = n & 15;
      wsp[OFF_W1 + (nt * 3 + kt) * 512 + (khi * 16 + lo) * 8 + j] =
          f2bf(((const float*)&v4)[r]);
    }
  } else if (off < OFF_WK) {
    const int i = off - OFF_WQ;
    v4 = *(const float4*)(inw + (i >> 7) * 384 + (i & 127));
#pragma unroll
    for (int r = 0; r < 4; ++r) {
      const int ie = i + r;
      const int k = ie >> 7, n = ie & 127;
      const int kt = k >> 5, kr = k & 31, j = kr & 7, khi = kr >> 3;
      const int nt = n >> 4, lo = n & 15;
      wsp[OFF_WQ + (nt * 4 + kt) * 512 + (khi * 16 + lo) * 8 + j] =
          f2bf(((const float*)&v4)[r] * 0.17677669529663687f);
    }
  } else if (off < OFF_WV) {
    const int i = off - OFF_WK;
    v4 = *(const float4*)(inw + (i >> 7) * 384 + 128 + (i & 127));
#pragma unroll
    for (int r = 0; r < 4; ++r) {
      const int ie = i + r;
      const int m = ie >> 7, c = ie & 127;
      const int h = c >> 5, d = c & 31;
      const int nt = m >> 4;
      const int l = (d >> 3) * 16 + (m & 15);
      wsp[OFF_WK + (h * 8 + nt) * 512 + l * 8 + (d & 7)] =
          f2bf(((const float*)&v4)[r]);
    }
  } else if (off < OFF_WO) {
    const int i = off - OFF_WV;
    v4 = *(const float4*)(inw + (i >> 7) * 384 + 256 + (i & 127));
#pragma unroll
    for (int r = 0; r < 4; ++r) {
      const int ie = i + r;
      const int m = ie >> 7, c = ie & 127;
      const int h = c >> 5, d = c & 31;
      const int kt = m >> 5, mr = m & 31, j = mr & 7, mhi = mr >> 3;
      const int mt = d >> 4, lo = d & 15;
      wsp[OFF_WV + ((h * 2 + mt) * 4 + kt) * 512 + (mhi * 16 + lo) * 8 + j] =
          f2bf(((const float*)&v4)[r]);
    }
  } else if (off < OFF_W2) {
    const int i = off - OFF_WO;
    v4 = *(const float4*)(outw + i);
#pragma unroll
    for (int r = 0; r < 4; ++r) {
      const int ie = i + r;
      const int k = ie >> 7, n = ie & 127;
      const int kt = k >> 5, kr = k & 31, j = kr & 7, khi = kr >> 3;
      const int nt = n >> 4, lo = n & 15;
      wsp[OFF_WO + (nt * 4 + kt) * 512 + (khi * 16 + lo) * 8 + j] =
          f2bf(((const float*)&v4)[r]);
    }
  } else {
    const int i = off - OFF_W2;
    v4 = *(const float4*)(fc2w + i);
#pragma unroll
    for (int r = 0; r < 4; ++r) {
      const int ie = i + r;
      const int k = ie >> 5, n = ie & 31;
      const int kt = k >> 5, kr = k & 31, j = kr & 7, khi = kr >> 3;
      const int nt = n >> 4, lo = n & 15;
      wsp[OFF_W2 + (nt * 4 + kt) * 512 + (khi * 16 + lo) * 8 + j] =
          f2bf(((const float*)&v4)[r]);
    }
  }
}

// LDS (bytes) — R9 overlay map:
//   sx1 / vtbuf [128][136]bf16   0..34816   (x1, then V^T overlay rows h*32..)
//   sSlice 4x[16][136]           34816..52224  (per-wave transpose slices)
//     sattn [16][136] ALIASES sSlice+0     (live only after B2; slices dead)
//     sout  [16][136] ALIASES sSlice+4352  (live only after B3)
//   sres f32[32]                 52224..52352
//   sm   u8[128]                 52352..52480
// 52,480 B/block -> 3 blocks/CU (was 61,184 -> 2 blocks/CU).
#define SMEM_BYTES 52480

__global__ __launch_bounds__(256, 3) void qmix_mfma(
    const float* __restrict__ agent_qs, const float* __restrict__ entities,
    const unsigned char* __restrict__ emask_g,
    const unsigned short* __restrict__ wsw, const int* __restrict__ mflag,
    const float* __restrict__ w_fc1b, const float* __restrict__ w_outb,
    const float* __restrict__ w_fc2b, const float* __restrict__ v_fc1b,
    const float* __restrict__ v_outb, const float* __restrict__ v_fc2b,
    float* __restrict__ out_g) {
  const int t = threadIdx.x;
  const int wv = t >> 6;  // wave == head
  const int ln = t & 63;
  const int lr = ln & 15;
  const int lq = ln >> 4;
  const int b = blockIdx.x;
  const float* ents = entities + (size_t)b * (NEn * EDm);

  __shared__ __align__(16) unsigned char smem[SMEM_BYTES];
  unsigned short* sx1 = (unsigned short*)smem;  // also vtbuf
  unsigned short* sSlice = sx1 + 17408;         // 4 slices
  unsigned short* sattn = sSlice;               // alias: live post-B2 only
  unsigned short* sout = sSlice + 16 * ST;      // alias: live post-B3 only
  float* sres = (float*)(smem + 52224);
  unsigned char* sm = smem + 52352;
  unsigned short* sS = sSlice + wv * 16 * ST;  // this wave's slice

  // ---- entity mask (dtype-normalized) ----
  const int is_i32 = *mflag;
  int mv = 1;
  if (t < NEn) {
    if (is_i32)
      mv = (((const int*)emask_g)[(size_t)b * NEn + t] != 0) ? 1 : 0;
    else
      mv = (emask_g[(size_t)b * NEn + t] != 0) ? 1 : 0;
    sm[t] = (unsigned char)mv;
  }
  const int allE = __syncthreads_and(mv);

  for (int p = 0; p < 2; ++p) {
    const unsigned short* wsb = wsw + (size_t)p * HYPE;
    const float* fc1b = p ? v_fc1b : w_fc1b;
    const float* outb = p ? v_outb : w_outb;
    const float* fc2b = p ? v_fc2b : w_fc2b;

    // ---- Phase A (co-op): x1 = relu(E @ W1 + b) -> sx1 [e][m] ----
    {
#pragma unroll
      for (int mi = 0; mi < 2; ++mi) {
        const int mt = wv * 2 + mi;
        bf16x8 af[3];
        const float* erow = ents + (mt * 16 + lr) * EDm + lq * 8;
#pragma unroll
        for (int kt = 0; kt < 3; ++kt) {
          float4 u = *(const float4*)(erow + kt * 32);
          float4 v = *(const float4*)(erow + kt * 32 + 4);
          bf16x8 a;
          a[0] = (short)f2bf(u.x); a[1] = (short)f2bf(u.y);
          a[2] = (short)f2bf(u.z); a[3] = (short)f2bf(u.w);
          a[4] = (short)f2bf(v.x); a[5] = (short)f2bf(v.y);
          a[6] = (short)f2bf(v.z); a[7] = (short)f2bf(v.w);
          af[kt] = a;
        }
        for (int nt = 0; nt < 8; ++nt) {
          f32x4 acc = {0.f, 0.f, 0.f, 0.f};
          const unsigned short* bp = wsb + OFF_W1 + (nt * 3) * 512 + ln * 8;
#pragma unroll
          for (int kt = 0; kt < 3; ++kt)
            acc = MFMA(af[kt], *(const bf16x8*)(bp + kt * 512), acc);
          const float bias = fc1b[nt * 16 + lr];
          f32x4 r;
          r[0] = fmaxf(acc[0] + bias, 0.f); r[1] = fmaxf(acc[1] + bias, 0.f);
          r[2] = fmaxf(acc[2] + bias, 0.f); r[3] = fmaxf(acc[3] + bias, 0.f);
          ctile_store(sx1, mt * 16 + lq * 4, nt * 16 + lr, r);
        }
      }
    }
    __syncthreads();  // B1: x1 complete (also fences prior sout/slice reads)

    // ---- Q (own head): Q_h[q][d] -> transpose via slice -> aQ ----
    {
      bf16x8 aq[4];
#pragma unroll
      for (int kt = 0; kt < 4; ++kt)
        aq[kt] = *(const bf16x8*)(sx1 + lr * ST + kt * 32 + lq * 8);
#pragma unroll
      for (int ni = 0; ni < 2; ++ni) {
        const int nt = wv * 2 + ni;
        f32x4 acc = {0.f, 0.f, 0.f, 0.f};
        const unsigned short* bp = wsb + OFF_WQ + (nt * 4) * 512 + ln * 8;
#pragma unroll
        for (int kt = 0; kt < 4; ++kt)
          acc = MFMA(aq[kt], *(const bf16x8*)(bp + kt * 512), acc);
        ctile_store(sS, lq * 4, ni * 16 + lr, acc);  // local d cols 0..31
      }
    }
    LGKM0();
    const bf16x8 aQ = *(const bf16x8*)(sS + lr * ST + lq * 8);  // A[q][d0..31]

    // ---- qW = Q_h @ Wk_h^T (8 m-tiles) -> transpose -> aw ----
    {
      f32x4 Cw[8];
#pragma unroll
      for (int nt = 0; nt < 8; ++nt) {
        f32x4 acc = {0.f, 0.f, 0.f, 0.f};
        Cw[nt] = MFMA(aQ, *(const bf16x8*)(wsb + OFF_WK + (wv * 8 + nt) * 512 +
                                           ln * 8),
                      acc);
      }
#pragma unroll
      for (int nt = 0; nt < 8; ++nt)
        ctile_store(sS, lq * 4, nt * 16 + lr, Cw[nt]);
    }
    LGKM0();
    bf16x8 aw[4];
#pragma unroll
    for (int kt = 0; kt < 4; ++kt)
      aw[kt] = *(const bf16x8*)(sS + lr * ST + kt * 32 + lq * 8);

    // ---- logits (full width, in-wave): Cl[nt] = qW @ x1^T ----
    f32x4 Cl[8];
#pragma unroll
    for (int nt = 0; nt < 8; ++nt) {
      f32x4 acc = {0.f, 0.f, 0.f, 0.f};
#pragma unroll
      for (int kt = 0; kt < 4; ++kt) {
        const bf16x8 bx =
            *(const bf16x8*)(sx1 + (nt * 16 + lr) * ST + kt * 32 + lq * 8);
        acc = MFMA(aw[kt], bx, acc);
      }
      Cl[nt] = acc;
    }

    // ---- in-wave softmax over 128 cols ----
    {
      float lv[8][4];
#pragma unroll
      for (int nt = 0; nt < 8; ++nt) {
        const int eM = sm[nt * 16 + lr];
#pragma unroll
        for (int r = 0; r < 4; ++r) lv[nt][r] = eM ? -1e9f : Cl[nt][r];
      }
      float mx[4], sl[4];
#pragma unroll
      for (int r = 0; r < 4; ++r) {
        float m = lv[0][r];
#pragma unroll
        for (int nt = 1; nt < 8; ++nt) m = fmaxf(m, lv[nt][r]);
        mx[r] = m;
      }
#pragma unroll
      for (int k = 1; k < 16; k <<= 1)
#pragma unroll
        for (int r = 0; r < 4; ++r) mx[r] = fmaxf(mx[r], __shfl_xor(mx[r], k));
      float ex[8][4];
#pragma unroll
      for (int r = 0; r < 4; ++r) sl[r] = 0.f;
#pragma unroll
      for (int nt = 0; nt < 8; ++nt)
#pragma unroll
        for (int r = 0; r < 4; ++r) {
          ex[nt][r] = __expf(lv[nt][r] - mx[r]);
          sl[r] += ex[nt][r];
        }
#pragma unroll
      for (int k = 1; k < 16; k <<= 1)
#pragma unroll
        for (int r = 0; r < 4; ++r) sl[r] += __shfl_xor(sl[r], k);
      float sc[4];
#pragma unroll
      for (int r = 0; r < 4; ++r)
        sc[r] = ((int)sm[lq * 4 + r] | allE) ? 0.f : (1.f / sl[r]);
#pragma unroll
      for (int nt = 0; nt < 8; ++nt) {
        f32x4 wv4;
#pragma unroll
        for (int r = 0; r < 4; ++r) wv4[r] = ex[nt][r] * sc[r];
        ctile_store(sS, lq * 4, nt * 16 + lr, wv4);  // W, overwrites qW
      }
    }
    LGKM0();
    bf16x8 aw2[4];
#pragma unroll
    for (int kt = 0; kt < 4; ++kt)
      aw2[kt] = *(const bf16x8*)(sS + lr * ST + kt * 32 + lq * 8);
    // sS (all slices) dead from here until next p's Q phase (post-next-B1).

    // ---- V^T_h = Wv_h^T @ x1^T into regs (x1 still live) ----
    f32x4 Cv[2][8];
#pragma unroll
    for (int mt = 0; mt < 2; ++mt) {
      bf16x8 av[4];
#pragma unroll
      for (int kt = 0; kt < 4; ++kt)
        av[kt] = *(const bf16x8*)(wsb + OFF_WV +
                                  (((wv * 2 + mt) * 4) + kt) * 512 + ln * 8);
#pragma unroll
      for (int nt = 0; nt < 8; ++nt) {
        f32x4 acc = {0.f, 0.f, 0.f, 0.f};
#pragma unroll
        for (int kt = 0; kt < 4; ++kt) {
          const bf16x8 bx =
              *(const bf16x8*)(sx1 + (nt * 16 + lr) * ST + kt * 32 + lq * 8);
          acc = MFMA(av[kt], bx, acc);
        }
        Cv[mt][nt] = acc;
      }
    }
    __syncthreads();  // B2: x1 dead -> vtbuf; slices dead -> sattn valid

    // ---- write V^T into own 32-row band of vtbuf; attn = W @ V_h ----
    {
#pragma unroll
      for (int mt = 0; mt < 2; ++mt)
#pragma unroll
        for (int nt = 0; nt < 8; ++nt)
          ctile_store(sx1, wv * 32 + mt * 16 + lq * 4, nt * 16 + lr,
                      Cv[mt][nt]);
    }
    LGKM0();
    {
#pragma unroll
      for (int ntd = 0; ntd < 2; ++ntd) {
        f32x4 acc = {0.f, 0.f, 0.f, 0.f};
#pragma unroll
        for (int kt = 0; kt < 4; ++kt) {
          const bf16x8 bv = *(const bf16x8*)(sx1 + (wv * 32 + ntd * 16 + lr) *
                                                       ST +
                                             kt * 32 + lq * 8);
          acc = MFMA(aw2[kt], bv, acc);
        }
        ctile_store(sattn, lq * 4, wv * 32 + ntd * 16 + lr, acc);
      }
    }
    __syncthreads();  // B3: sattn complete; sout region (slice 1) writable

    // ---- OUT = attn @ Wo + bo -> sout (co-op, 2 n-tiles/wave) ----
    {
      bf16x8 aa[4];
#pragma unroll
      for (int kt = 0; kt < 4; ++kt)
        aa[kt] = *(const bf16x8*)(sattn + lr * ST + kt * 32 + lq * 8);
#pragma unroll
      for (int ni = 0; ni < 2; ++ni) {
        const int nt = wv * 2 + ni;
        f32x4 acc = {0.f, 0.f, 0.f, 0.f};
        const unsigned short* bp = wsb + OFF_WO + (nt * 4) * 512 + ln * 8;
#pragma unroll
        for (int kt = 0; kt < 4; ++kt)
          acc = MFMA(aa[kt], *(const bf16x8*)(bp + kt * 512), acc);
        const float bj = outb[nt * 16 + lr];
        f32x4 r;
        r[0] = acc[0] + bj; r[1] = acc[1] + bj;
        r[2] = acc[2] + bj; r[3] = acc[3] + bj;
        ctile_store(sout, lq * 4, nt * 16 + lr, r);
      }
    }
    __syncthreads();  // B4: sout complete

    // ---- X3 = out @ fc2 + b (redundant per wave), mask, row-sum ----
    {
      bf16x8 ao[4];
#pragma unroll
      for (int kt = 0; kt < 4; ++kt)
        ao[kt] = *(const bf16x8*)(sout + lr * ST + kt * 32 + lq * 8);
      f32x4 Cx[2];
#pragma unroll
      for (int nt = 0; nt < 2; ++nt) {
        f32x4 acc = {0.f, 0.f, 0.f, 0.f};
        const unsigned short* bp = wsb + OFF_W2 + (nt * 4) * 512 + ln * 8;
#pragma unroll
        for (int kt = 0; kt < 4; ++kt)
          acc = MFMA(ao[kt], *(const bf16x8*)(bp + kt * 512), acc);
        Cx[nt] = acc;
      }
      const float b0 = fc2b[lr], b1 = fc2b[16 + lr];
      float rs[4];
#pragma unroll
      for (int r = 0; r < 4; ++r) {
        const int row = lq * 4 + r;
        rs[r] = sm[row] ? 0.f : (Cx[0][r] + b0 + Cx[1][r] + b1);
      }
#pragma unroll
      for (int k = 1; k < 16; k <<= 1)
#pragma unroll
        for (int r = 0; r < 4; ++r) rs[r] += __shfl_xor(rs[r], k);
      if (wv == 0 && lr == 0) {
#pragma unroll
        for (int r = 0; r < 4; ++r) {
          const int q = lq * 4 + r;
          sres[p * 16 + q] = p ? rs[r] : fabsf(rs[r]) * (1.f / 32.f);
        }
      }
    }
  }  // p

  __syncthreads();
  if (t == 0) {
    const float* qs = agent_qs + (size_t)b * NA;
    float tot = 0.f, vs = 0.f;
#pragma unroll
    for (int q = 0; q < NA; ++q) {
      tot += qs[q] * sres[q];
      vs += sres[16 + q];
    }
    out_g[b] = tot + vs * (1.f / 512.f);
  }
}

extern "C" void kernel_launch(void* const* d_in, const int* in_sizes, int n_in,
                              void* d_out, int out_size, void* d_ws,
                              size_t ws_size, hipStream_t stream) {
  (void)n_in; (void)out_size; (void)ws_size;
  const int nb = in_sizes[0] / NA;  // BS*T = 1600
  unsigned short* wsw = (unsigned short*)d_ws;
  int* mflag = (int*)((char*)d_ws + WS_FLAG_OFF);

  hipLaunchKernelGGL(prep_kernel, dim3(161), dim3(256), 0, stream,
                     (const float*)d_in[3], (const float*)d_in[5],
                     (const float*)d_in[6], (const float*)d_in[8],
                     (const float*)d_in[10], (const float*)d_in[12],
                     (const float*)d_in[13], (const float*)d_in[15],
                     (const unsigned char*)d_in[2], wsw, mflag);
  hipLaunchKernelGGL(qmix_mfma, dim3(nb), dim3(256), 0, stream,
                     (const float*)d_in[0], (const float*)d_in[1],
                     (const unsigned char*)d_in[2], (const unsigned short*)wsw,
                     (const int*)mflag, (const float*)d_in[4],
                     (const float*)d_in[7], (const float*)d_in[9],
                     (const float*)d_in[11], (const float*)d_in[14],
                     (const float*)d_in[16], (float*)d_out);
}

// Round 2
// 268.995 us; speedup vs baseline: 1.3988x; 1.3988x over previous
//
#include <hip/hip_runtime.h>

// LinearFlexQMixer MI355X — round 10: keep R9's LDS overlay, revert launch
// bounds. R9 post-mortem: __launch_bounds__(256,3) capped VGPRs 128->84 ->
// mass scratch spills (FETCH 45->159MB, WRITE 16->160MB) -> 265us. The LDS
// overlay itself worked (52.7KB -> 3 blocks/CU resource limit). Fix: bounds
// back to (256,2) — the 2nd arg is only an allocator floor; with 128 VGPR
// (4 waves/SIMD ok) and 52.7KB LDS the achieved occupancy is still 3
// blocks/CU, spill-free.

#define NA 16
#define NEn 128
#define EDm 96
#define ST 136  // LDS row stride (shorts); 272B rows -> <=2-way conflicts

typedef __attribute__((ext_vector_type(8))) short bf16x8;
typedef __attribute__((ext_vector_type(4))) float f32x4;

#define MFMA(a, b, c) __builtin_amdgcn_mfma_f32_16x16x32_bf16((a), (b), (c), 0, 0, 0)
#define LGKM0() __asm__ volatile("s_waitcnt lgkmcnt(0)" ::: "memory")

// d_ws layout (bf16 elems), per hypernet p at p*HYPE:
#define OFF_W1 0       // [nt8][kt3][64][8]  B-frags Phase A (fc1w)
#define OFF_WQ 12288   // [nt8][kt4][64][8]  B-frags Q (inw cols 0:128, pre-scaled)
#define OFF_WK 28672   // [h4][nt8][64][8]   B-frags qW (Wk^T per head, K=32)
#define OFF_WV 45056   // [h4][mt2][kt4][64][8] A-frags V^T (Wv^T per head)
#define OFF_WO 61440   // [nt8][kt4][64][8]  B-frags OUT (outw)
#define OFF_W2 77824   // [nt2][kt4][64][8]  B-frags X3 (fc2w)
#define HYPE 81920
#define WS_FLAG_OFF 327680  // int flag: mask dtype (1 => int32)

__device__ __forceinline__ unsigned short f2bf(float f) {
  unsigned u = __float_as_uint(f);
  u += 0x7fffu + ((u >> 16) & 1u);  // RNE
  return (unsigned short)(u >> 16);
}

// Store one 16x16 C-tile column (4 f32, rows row0+0..3, col) as bf16 into
// LDS row-major [..][ST]. Pairs lanes (col, col^1) via shfl so every dword
// is written by exactly one lane. Full-wave calls only.
__device__ __forceinline__ void ctile_store(unsigned short* dst, int row0,
                                            int col, f32x4 v) {
  unsigned short m0 = f2bf(v[0]), m1 = f2bf(v[1]), m2 = f2bf(v[2]),
                 m3 = f2bf(v[3]);
  unsigned x = (unsigned)m0 | ((unsigned)m1 << 16);
  unsigned y = (unsigned)m2 | ((unsigned)m3 << 16);
  unsigned ox = (unsigned)__shfl_xor((int)x, 1);
  unsigned oy = (unsigned)__shfl_xor((int)y, 1);
  unsigned w0, w1;
  int ra;
  if ((threadIdx.x & 1) == 0) {
    ra = 0;
    w0 = (x & 0xffffu) | (ox << 16);
    w1 = (x >> 16) | (ox & 0xffff0000u);
  } else {
    ra = 2;
    w0 = (oy & 0xffffu) | (y << 16);
    w1 = (oy >> 16) | (y & 0xffff0000u);
  }
  *(unsigned*)(dst + (row0 + ra) * ST + (col & ~1)) = w0;
  *(unsigned*)(dst + (row0 + ra + 1) * ST + (col & ~1)) = w1;
}

// ---- prep: 160 work blocks (one float4/thread, source-order) + 1 mask blk
__global__ void prep_kernel(const float* __restrict__ w_fc1w,
                            const float* __restrict__ w_inw,
                            const float* __restrict__ w_outw,
                            const float* __restrict__ w_fc2w,
                            const float* __restrict__ v_fc1w,
                            const float* __restrict__ v_inw,
                            const float* __restrict__ v_outw,
                            const float* __restrict__ v_fc2w,
                            const unsigned char* __restrict__ mask,
                            unsigned short* __restrict__ ws,
                            int* __restrict__ flag) {
  if (blockIdx.x == 160) {
    const uint4 v = *(const uint4*)(mask + threadIdx.x * 16);
    const unsigned nz = (v.x | v.y | v.z | v.w) & 0xffffff00u;
    const int any = __syncthreads_or((int)(nz != 0));
    if (threadIdx.x == 0) *flag = (any == 0) ? 1 : 0;
    return;
  }
  const int g = blockIdx.x * 256 + threadIdx.x;  // 0 .. 40959
  const int p = (g >= 20480) ? 1 : 0;
  const int off = (g - p * 20480) * 4;
  const float* fc1w = p ? v_fc1w : w_fc1w;
  const float* inw = p ? v_inw : w_inw;
  const float* outw = p ? v_outw : w_outw;
  const float* fc2w = p ? v_fc2w : w_fc2w;
  unsigned short* wsp = ws + p * HYPE;

  float4 v4;
  if (off < OFF_WQ) {
    v4 = *(const float4*)(fc1w + off);
#pragma unroll
    for (int r = 0; r < 4; ++r) {
      const int oe = off + r;
      const int k = oe >> 7, n = oe & 127;
      const int kt = k >> 5, kr = k & 31, j = kr & 7, khi = kr >> 3;
      const int nt = n >> 4, lo = n & 15;
      wsp[OFF_W1 + (nt * 3 + kt) * 512 + (khi * 16 + lo) * 8 + j] =
          f2bf(((const float*)&v4)[r]);
    }
  } else if (off < OFF_WK) {
    const int i = off - OFF_WQ;
    v4 = *(const float4*)(inw + (i >> 7) * 384 + (i & 127));
#pragma unroll
    for (int r = 0; r < 4; ++r) {
      const int ie = i + r;
      const int k = ie >> 7, n = ie & 127;
      const int kt = k >> 5, kr = k & 31, j = kr & 7, khi = kr >> 3;
      const int nt = n >> 4, lo = n & 15;
      wsp[OFF_WQ + (nt * 4 + kt) * 512 + (khi * 16 + lo) * 8 + j] =
          f2bf(((const float*)&v4)[r] * 0.17677669529663687f);
    }
  } else if (off < OFF_WV) {
    const int i = off - OFF_WK;
    v4 = *(const float4*)(inw + (i >> 7) * 384 + 128 + (i & 127));
#pragma unroll
    for (int r = 0; r < 4; ++r) {
      const int ie = i + r;
      const int m = ie >> 7, c = ie & 127;
      const int h = c >> 5, d = c & 31;
      const int nt = m >> 4;
      const int l = (d >> 3) * 16 + (m & 15);
      wsp[OFF_WK + (h * 8 + nt) * 512 + l * 8 + (d & 7)] =
          f2bf(((const float*)&v4)[r]);
    }
  } else if (off < OFF_WO) {
    const int i = off - OFF_WV;
    v4 = *(const float4*)(inw + (i >> 7) * 384 + 256 + (i & 127));
#pragma unroll
    for (int r = 0; r < 4; ++r) {
      const int ie = i + r;
      const int m = ie >> 7, c = ie & 127;
      const int h = c >> 5, d = c & 31;
      const int kt = m >> 5, mr = m & 31, j = mr & 7, mhi = mr >> 3;
      const int mt = d >> 4, lo = d & 15;
      wsp[OFF_WV + ((h * 2 + mt) * 4 + kt) * 512 + (mhi * 16 + lo) * 8 + j] =
          f2bf(((const float*)&v4)[r]);
    }
  } else if (off < OFF_W2) {
    const int i = off - OFF_WO;
    v4 = *(const float4*)(outw + i);
#pragma unroll
    for (int r = 0; r < 4; ++r) {
      const int ie = i + r;
      const int k = ie >> 7, n = ie & 127;
      const int kt = k >> 5, kr = k & 31, j = kr & 7, khi = kr >> 3;
      const int nt = n >> 4, lo = n & 15;
      wsp[OFF_WO + (nt * 4 + kt) * 512 + (khi * 16 + lo) * 8 + j] =
          f2bf(((const float*)&v4)[r]);
    }
  } else {
    const int i = off - OFF_W2;
    v4 = *(const float4*)(fc2w + i);
#pragma unroll
    for (int r = 0; r < 4; ++r) {
      const int ie = i + r;
      const int k = ie >> 5, n = ie & 31;
      const int kt = k >> 5, kr = k & 31, j = kr & 7, khi = kr >> 3;
      const int nt = n >> 4, lo = n & 15;
      wsp[OFF_W2 + (nt * 4 + kt) * 512 + (khi * 16 + lo) * 8 + j] =
          f2bf(((const float*)&v4)[r]);
    }
  }
}

// LDS (bytes) — overlay map:
//   sx1 / vtbuf [128][136]bf16   0..34816   (x1, then V^T overlay rows h*32..)
//   sSlice 4x[16][136]           34816..52224  (per-wave transpose slices)
//     sattn [16][136] ALIASES sSlice+0     (live only after B2; slices dead)
//     sout  [16][136] ALIASES sSlice+4352  (live only after B3)
//   sres f32[32]                 52224..52352
//   sm   u8[128]                 52352..52480
// 52,480 B/block -> 3 blocks/CU resource limit (160KB/CU).
#define SMEM_BYTES 52480

__global__ __launch_bounds__(256, 2) void qmix_mfma(
    const float* __restrict__ agent_qs, const float* __restrict__ entities,
    const unsigned char* __restrict__ emask_g,
    const unsigned short* __restrict__ wsw, const int* __restrict__ mflag,
    const float* __restrict__ w_fc1b, const float* __restrict__ w_outb,
    const float* __restrict__ w_fc2b, const float* __restrict__ v_fc1b,
    const float* __restrict__ v_outb, const float* __restrict__ v_fc2b,
    float* __restrict__ out_g) {
  const int t = threadIdx.x;
  const int wv = t >> 6;  // wave == head
  const int ln = t & 63;
  const int lr = ln & 15;
  const int lq = ln >> 4;
  const int b = blockIdx.x;
  const float* ents = entities + (size_t)b * (NEn * EDm);

  __shared__ __align__(16) unsigned char smem[SMEM_BYTES];
  unsigned short* sx1 = (unsigned short*)smem;  // also vtbuf
  unsigned short* sSlice = sx1 + 17408;         // 4 slices
  unsigned short* sattn = sSlice;               // alias: live post-B2 only
  unsigned short* sout = sSlice + 16 * ST;      // alias: live post-B3 only
  float* sres = (float*)(smem + 52224);
  unsigned char* sm = smem + 52352;
  unsigned short* sS = sSlice + wv * 16 * ST;  // this wave's slice

  // ---- entity mask (dtype-normalized) ----
  const int is_i32 = *mflag;
  int mv = 1;
  if (t < NEn) {
    if (is_i32)
      mv = (((const int*)emask_g)[(size_t)b * NEn + t] != 0) ? 1 : 0;
    else
      mv = (emask_g[(size_t)b * NEn + t] != 0) ? 1 : 0;
    sm[t] = (unsigned char)mv;
  }
  const int allE = __syncthreads_and(mv);

  for (int p = 0; p < 2; ++p) {
    const unsigned short* wsb = wsw + (size_t)p * HYPE;
    const float* fc1b = p ? v_fc1b : w_fc1b;
    const float* outb = p ? v_outb : w_outb;
    const float* fc2b = p ? v_fc2b : w_fc2b;

    // ---- Phase A (co-op): x1 = relu(E @ W1 + b) -> sx1 [e][m] ----
    {
#pragma unroll
      for (int mi = 0; mi < 2; ++mi) {
        const int mt = wv * 2 + mi;
        bf16x8 af[3];
        const float* erow = ents + (mt * 16 + lr) * EDm + lq * 8;
#pragma unroll
        for (int kt = 0; kt < 3; ++kt) {
          float4 u = *(const float4*)(erow + kt * 32);
          float4 v = *(const float4*)(erow + kt * 32 + 4);
          bf16x8 a;
          a[0] = (short)f2bf(u.x); a[1] = (short)f2bf(u.y);
          a[2] = (short)f2bf(u.z); a[3] = (short)f2bf(u.w);
          a[4] = (short)f2bf(v.x); a[5] = (short)f2bf(v.y);
          a[6] = (short)f2bf(v.z); a[7] = (short)f2bf(v.w);
          af[kt] = a;
        }
        for (int nt = 0; nt < 8; ++nt) {
          f32x4 acc = {0.f, 0.f, 0.f, 0.f};
          const unsigned short* bp = wsb + OFF_W1 + (nt * 3) * 512 + ln * 8;
#pragma unroll
          for (int kt = 0; kt < 3; ++kt)
            acc = MFMA(af[kt], *(const bf16x8*)(bp + kt * 512), acc);
          const float bias = fc1b[nt * 16 + lr];
          f32x4 r;
          r[0] = fmaxf(acc[0] + bias, 0.f); r[1] = fmaxf(acc[1] + bias, 0.f);
          r[2] = fmaxf(acc[2] + bias, 0.f); r[3] = fmaxf(acc[3] + bias, 0.f);
          ctile_store(sx1, mt * 16 + lq * 4, nt * 16 + lr, r);
        }
      }
    }
    __syncthreads();  // B1: x1 complete (also fences prior sout/slice reads)

    // ---- Q (own head): Q_h[q][d] -> transpose via slice -> aQ ----
    {
      bf16x8 aq[4];
#pragma unroll
      for (int kt = 0; kt < 4; ++kt)
        aq[kt] = *(const bf16x8*)(sx1 + lr * ST + kt * 32 + lq * 8);
#pragma unroll
      for (int ni = 0; ni < 2; ++ni) {
        const int nt = wv * 2 + ni;
        f32x4 acc = {0.f, 0.f, 0.f, 0.f};
        const unsigned short* bp = wsb + OFF_WQ + (nt * 4) * 512 + ln * 8;
#pragma unroll
        for (int kt = 0; kt < 4; ++kt)
          acc = MFMA(aq[kt], *(const bf16x8*)(bp + kt * 512), acc);
        ctile_store(sS, lq * 4, ni * 16 + lr, acc);  // local d cols 0..31
      }
    }
    LGKM0();
    const bf16x8 aQ = *(const bf16x8*)(sS + lr * ST + lq * 8);  // A[q][d0..31]

    // ---- qW = Q_h @ Wk_h^T (8 m-tiles) -> transpose -> aw ----
    {
      f32x4 Cw[8];
#pragma unroll
      for (int nt = 0; nt < 8; ++nt) {
        f32x4 acc = {0.f, 0.f, 0.f, 0.f};
        Cw[nt] = MFMA(aQ, *(const bf16x8*)(wsb + OFF_WK + (wv * 8 + nt) * 512 +
                                           ln * 8),
                      acc);
      }
#pragma unroll
      for (int nt = 0; nt < 8; ++nt)
        ctile_store(sS, lq * 4, nt * 16 + lr, Cw[nt]);
    }
    LGKM0();
    bf16x8 aw[4];
#pragma unroll
    for (int kt = 0; kt < 4; ++kt)
      aw[kt] = *(const bf16x8*)(sS + lr * ST + kt * 32 + lq * 8);

    // ---- logits (full width, in-wave): Cl[nt] = qW @ x1^T ----
    f32x4 Cl[8];
#pragma unroll
    for (int nt = 0; nt < 8; ++nt) {
      f32x4 acc = {0.f, 0.f, 0.f, 0.f};
#pragma unroll
      for (int kt = 0; kt < 4; ++kt) {
        const bf16x8 bx =
            *(const bf16x8*)(sx1 + (nt * 16 + lr) * ST + kt * 32 + lq * 8);
        acc = MFMA(aw[kt], bx, acc);
      }
      Cl[nt] = acc;
    }

    // ---- in-wave softmax over 128 cols ----
    {
      float lv[8][4];
#pragma unroll
      for (int nt = 0; nt < 8; ++nt) {
        const int eM = sm[nt * 16 + lr];
#pragma unroll
        for (int r = 0; r < 4; ++r) lv[nt][r] = eM ? -1e9f : Cl[nt][r];
      }
      float mx[4], sl[4];
#pragma unroll
      for (int r = 0; r < 4; ++r) {
        float m = lv[0][r];
#pragma unroll
        for (int nt = 1; nt < 8; ++nt) m = fmaxf(m, lv[nt][r]);
        mx[r] = m;
      }
#pragma unroll
      for (int k = 1; k < 16; k <<= 1)
#pragma unroll
        for (int r = 0; r < 4; ++r) mx[r] = fmaxf(mx[r], __shfl_xor(mx[r], k));
      float ex[8][4];
#pragma unroll
      for (int r = 0; r < 4; ++r) sl[r] = 0.f;
#pragma unroll
      for (int nt = 0; nt < 8; ++nt)
#pragma unroll
        for (int r = 0; r < 4; ++r) {
          ex[nt][r] = __expf(lv[nt][r] - mx[r]);
          sl[r] += ex[nt][r];
        }
#pragma unroll
      for (int k = 1; k < 16; k <<= 1)
#pragma unroll
        for (int r = 0; r < 4; ++r) sl[r] += __shfl_xor(sl[r], k);
      float sc[4];
#pragma unroll
      for (int r = 0; r < 4; ++r)
        sc[r] = ((int)sm[lq * 4 + r] | allE) ? 0.f : (1.f / sl[r]);
#pragma unroll
      for (int nt = 0; nt < 8; ++nt) {
        f32x4 wv4;
#pragma unroll
        for (int r = 0; r < 4; ++r) wv4[r] = ex[nt][r] * sc[r];
        ctile_store(sS, lq * 4, nt * 16 + lr, wv4);  // W, overwrites qW
      }
    }
    LGKM0();
    bf16x8 aw2[4];
#pragma unroll
    for (int kt = 0; kt < 4; ++kt)
      aw2[kt] = *(const bf16x8*)(sS + lr * ST + kt * 32 + lq * 8);
    // sS (all slices) dead from here until next p's Q phase (post-next-B1).

    // ---- V^T_h = Wv_h^T @ x1^T into regs (x1 still live) ----
    f32x4 Cv[2][8];
#pragma unroll
    for (int mt = 0; mt < 2; ++mt) {
      bf16x8 av[4];
#pragma unroll
      for (int kt = 0; kt < 4; ++kt)
        av[kt] = *(const bf16x8*)(wsb + OFF_WV +
                                  (((wv * 2 + mt) * 4) + kt) * 512 + ln * 8);
#pragma unroll
      for (int nt = 0; nt < 8; ++nt) {
        f32x4 acc = {0.f, 0.f, 0.f, 0.f};
#pragma unroll
        for (int kt = 0; kt < 4; ++kt) {
          const bf16x8 bx =
              *(const bf16x8*)(sx1 + (nt * 16 + lr) * ST + kt * 32 + lq * 8);
          acc = MFMA(av[kt], bx, acc);
        }
        Cv[mt][nt] = acc;
      }
    }
    __syncthreads();  // B2: x1 dead -> vtbuf; slices dead -> sattn valid

    // ---- write V^T into own 32-row band of vtbuf; attn = W @ V_h ----
    {
#pragma unroll
      for (int mt = 0; mt < 2; ++mt)
#pragma unroll
        for (int nt = 0; nt < 8; ++nt)
          ctile_store(sx1, wv * 32 + mt * 16 + lq * 4, nt * 16 + lr,
                      Cv[mt][nt]);
    }
    LGKM0();
    {
#pragma unroll
      for (int ntd = 0; ntd < 2; ++ntd) {
        f32x4 acc = {0.f, 0.f, 0.f, 0.f};
#pragma unroll
        for (int kt = 0; kt < 4; ++kt) {
          const bf16x8 bv = *(const bf16x8*)(sx1 + (wv * 32 + ntd * 16 + lr) *
                                                       ST +
                                             kt * 32 + lq * 8);
          acc = MFMA(aw2[kt], bv, acc);
        }
        ctile_store(sattn, lq * 4, wv * 32 + ntd * 16 + lr, acc);
      }
    }
    __syncthreads();  // B3: sattn complete; sout region (slice 1) writable

    // ---- OUT = attn @ Wo + bo -> sout (co-op, 2 n-tiles/wave) ----
    {
      bf16x8 aa[4];
#pragma unroll
      for (int kt = 0; kt < 4; ++kt)
        aa[kt] = *(const bf16x8*)(sattn + lr * ST + kt * 32 + lq * 8);
#pragma unroll
      for (int ni = 0; ni < 2; ++ni) {
        const int nt = wv * 2 + ni;
        f32x4 acc = {0.f, 0.f, 0.f, 0.f};
        const unsigned short* bp = wsb + OFF_WO + (nt * 4) * 512 + ln * 8;
#pragma unroll
        for (int kt = 0; kt < 4; ++kt)
          acc = MFMA(aa[kt], *(const bf16x8*)(bp + kt * 512), acc);
        const float bj = outb[nt * 16 + lr];
        f32x4 r;
        r[0] = acc[0] + bj; r[1] = acc[1] + bj;
        r[2] = acc[2] + bj; r[3] = acc[3] + bj;
        ctile_store(sout, lq * 4, nt * 16 + lr, r);
      }
    }
    __syncthreads();  // B4: sout complete

    // ---- X3 = out @ fc2 + b (redundant per wave), mask, row-sum ----
    {
      bf16x8 ao[4];
#pragma unroll
      for (int kt = 0; kt < 4; ++kt)
        ao[kt] = *(const bf16x8*)(sout + lr * ST + kt * 32 + lq * 8);
      f32x4 Cx[2];
#pragma unroll
      for (int nt = 0; nt < 2; ++nt) {
        f32x4 acc = {0.f, 0.f, 0.f, 0.f};
        const unsigned short* bp = wsb + OFF_W2 + (nt * 4) * 512 + ln * 8;
#pragma unroll
        for (int kt = 0; kt < 4; ++kt)
          acc = MFMA(ao[kt], *(const bf16x8*)(bp + kt * 512), acc);
        Cx[nt] = acc;
      }
      const float b0 = fc2b[lr], b1 = fc2b[16 + lr];
      float rs[4];
#pragma unroll
      for (int r = 0; r < 4; ++r) {
        const int row = lq * 4 + r;
        rs[r] = sm[row] ? 0.f : (Cx[0][r] + b0 + Cx[1][r] + b1);
      }
#pragma unroll
      for (int k = 1; k < 16; k <<= 1)
#pragma unroll
        for (int r = 0; r < 4; ++r) rs[r] += __shfl_xor(rs[r], k);
      if (wv == 0 && lr == 0) {
#pragma unroll
        for (int r = 0; r < 4; ++r) {
          const int q = lq * 4 + r;
          sres[p * 16 + q] = p ? rs[r] : fabsf(rs[r]) * (1.f / 32.f);
        }
      }
    }
  }  // p

  __syncthreads();
  if (t == 0) {
    const float* qs = agent_qs + (size_t)b * NA;
    float tot = 0.f, vs = 0.f;
#pragma unroll
    for (int q = 0; q < NA; ++q) {
      tot += qs[q] * sres[q];
      vs += sres[16 + q];
    }
    out_g[b] = tot + vs * (1.f / 512.f);
  }
}

extern "C" void kernel_launch(void* const* d_in, const int* in_sizes, int n_in,
                              void* d_out, int out_size, void* d_ws,
                              size_t ws_size, hipStream_t stream) {
  (void)n_in; (void)out_size; (void)ws_size;
  const int nb = in_sizes[0] / NA;  // BS*T = 1600
  unsigned short* wsw = (unsigned short*)d_ws;
  int* mflag = (int*)((char*)d_ws + WS_FLAG_OFF);

  hipLaunchKernelGGL(prep_kernel, dim3(161), dim3(256), 0, stream,
                     (const float*)d_in[3], (const float*)d_in[5],
                     (const float*)d_in[6], (const float*)d_in[8],
                     (const float*)d_in[10], (const float*)d_in[12],
                     (const float*)d_in[13], (const float*)d_in[15],
                     (const unsigned char*)d_in[2], wsw, mflag);
  hipLaunchKernelGGL(qmix_mfma, dim3(nb), dim3(256), 0, stream,
                     (const float*)d_in[0], (const float*)d_in[1],
                     (const unsigned char*)d_in[2], (const unsigned short*)wsw,
                     (const int*)mflag, (const float*)d_in[4],
                     (const float*)d_in[7], (const float*)d_in[9],
                     (const float*)d_in[11], (const float*)d_in[14],
                     (const float*)d_in[16], (float*)d_out);
}

// Round 3
// 268.596 us; speedup vs baseline: 1.4008x; 1.0015x over previous
//
#include <hip/hip_runtime.h>

// LinearFlexQMixer MI355X — round 11: gather-style prep (coalesced stores).
// R10 post-mortem: qmix dropped 185->153.5us (overlay + 3 blk/CU, no spills)
// but bench stayed ~269us -> the ~115us gap is prep_kernel + overhead. Old
// prep did 655K scattered 2B stores (16 per thread). New prep inverts the
// mapping: each thread owns one 16B destination fragment row, gathers its 8
// source floats (dword gathers, weights are L2-resident ~655KB total), and
// issues ONE coalesced dwordx4 store. 20480 threads, 81 blocks.
// qmix_mfma is byte-identical to R10 (153.5us measured) for attribution.

#define NA 16
#define NEn 128
#define EDm 96
#define ST 136  // LDS row stride (shorts); 272B rows -> <=2-way conflicts

typedef __attribute__((ext_vector_type(8))) short bf16x8;
typedef __attribute__((ext_vector_type(4))) float f32x4;

#define MFMA(a, b, c) __builtin_amdgcn_mfma_f32_16x16x32_bf16((a), (b), (c), 0, 0, 0)
#define LGKM0() __asm__ volatile("s_waitcnt lgkmcnt(0)" ::: "memory")

// d_ws layout (bf16 elems), per hypernet p at p*HYPE:
#define OFF_W1 0       // [nt8][kt3][64][8]  B-frags Phase A (fc1w)
#define OFF_WQ 12288   // [nt8][kt4][64][8]  B-frags Q (inw cols 0:128, pre-scaled)
#define OFF_WK 28672   // [h4][nt8][64][8]   B-frags qW (Wk^T per head, K=32)
#define OFF_WV 45056   // [h4][mt2][kt4][64][8] A-frags V^T (Wv^T per head)
#define OFF_WO 61440   // [nt8][kt4][64][8]  B-frags OUT (outw)
#define OFF_W2 77824   // [nt2][kt4][64][8]  B-frags X3 (fc2w)
#define HYPE 81920
#define WS_FLAG_OFF 327680  // int flag: mask dtype (1 => int32)

__device__ __forceinline__ unsigned short f2bf(float f) {
  unsigned u = __float_as_uint(f);
  u += 0x7fffu + ((u >> 16) & 1u);  // RNE
  return (unsigned short)(u >> 16);
}

// Store one 16x16 C-tile column (4 f32, rows row0+0..3, col) as bf16 into
// LDS row-major [..][ST]. Pairs lanes (col, col^1) via shfl so every dword
// is written by exactly one lane. Full-wave calls only.
__device__ __forceinline__ void ctile_store(unsigned short* dst, int row0,
                                            int col, f32x4 v) {
  unsigned short m0 = f2bf(v[0]), m1 = f2bf(v[1]), m2 = f2bf(v[2]),
                 m3 = f2bf(v[3]);
  unsigned x = (unsigned)m0 | ((unsigned)m1 << 16);
  unsigned y = (unsigned)m2 | ((unsigned)m3 << 16);
  unsigned ox = (unsigned)__shfl_xor((int)x, 1);
  unsigned oy = (unsigned)__shfl_xor((int)y, 1);
  unsigned w0, w1;
  int ra;
  if ((threadIdx.x & 1) == 0) {
    ra = 0;
    w0 = (x & 0xffffu) | (ox << 16);
    w1 = (x >> 16) | (ox & 0xffff0000u);
  } else {
    ra = 2;
    w0 = (oy & 0xffffu) | (y << 16);
    w1 = (oy >> 16) | (y & 0xffff0000u);
  }
  *(unsigned*)(dst + (row0 + ra) * ST + (col & ~1)) = w0;
  *(unsigned*)(dst + (row0 + ra + 1) * ST + (col & ~1)) = w1;
}

// ---- prep (R11): destination-ordered gather. 80 work blocks + 1 mask blk.
// Thread g owns dest fragment row: p = g>=10240, i = g - p*10240,
// tile = i>>6 in [0,160), lane = i&63. Dest = region + tile*512 + lane*8,
// one bf16x8 (16B) coalesced store. Source: 8 gathered dwords.
// Tile map (per p): [0,24) W1 | [24,56) WQ | [56,88) WK | [88,120) WV |
//                   [120,152) WO | [152,160) W2.
__global__ void prep_kernel(const float* __restrict__ w_fc1w,
                            const float* __restrict__ w_inw,
                            const float* __restrict__ w_outw,
                            const float* __restrict__ w_fc2w,
                            const float* __restrict__ v_fc1w,
                            const float* __restrict__ v_inw,
                            const float* __restrict__ v_outw,
                            const float* __restrict__ v_fc2w,
                            const unsigned char* __restrict__ mask,
                            unsigned short* __restrict__ ws,
                            int* __restrict__ flag) {
  if (blockIdx.x == 80) {
    const uint4 v = *(const uint4*)(mask + threadIdx.x * 16);
    const unsigned nz = (v.x | v.y | v.z | v.w) & 0xffffff00u;
    const int any = __syncthreads_or((int)(nz != 0));
    if (threadIdx.x == 0) *flag = (any == 0) ? 1 : 0;
    return;
  }
  const int g = blockIdx.x * 256 + threadIdx.x;  // 0 .. 20479
  const int p = (g >= 10240) ? 1 : 0;
  const int i = g - p * 10240;
  const int l = i & 63;
  const int tt = i >> 6;  // 0..159
  const int lhi = l >> 4, lo = l & 15;
  const float* fc1w = p ? v_fc1w : w_fc1w;
  const float* inw = p ? v_inw : w_inw;
  const float* outw = p ? v_outw : w_outw;
  const float* fc2w = p ? v_fc2w : w_fc2w;
  unsigned short* wsp = ws + p * HYPE;

  float v8[8];
  unsigned short* dst;
  if (tt < 24) {
    // W1: t = nt*3+kt; src = fc1w[(kt*32+lhi*8+j)*128 + nt*16+lo]
    const int nt = tt / 3, kt = tt - nt * 3;
    const float* src = fc1w + (kt * 32 + lhi * 8) * 128 + nt * 16 + lo;
#pragma unroll
    for (int j = 0; j < 8; ++j) v8[j] = src[j * 128];
    dst = wsp + OFF_W1 + tt * 512 + l * 8;
  } else if (tt < 56) {
    // WQ: t2 = nt*4+kt; src = inw[(kt*32+lhi*8+j)*384 + nt*16+lo] * scale
    const int t2 = tt - 24;
    const int nt = t2 >> 2, kt = t2 & 3;
    const float* src = inw + (kt * 32 + lhi * 8) * 384 + nt * 16 + lo;
#pragma unroll
    for (int j = 0; j < 8; ++j) v8[j] = src[j * 384] * 0.17677669529663687f;
    dst = wsp + OFF_WQ + t2 * 512 + l * 8;
  } else if (tt < 88) {
    // WK: t2 = h*8+nt; src = inw[(nt*16+lo)*384 + 128 + h*32 + lhi*8 + j]
    const int t2 = tt - 56;
    const int h = t2 >> 3, nt = t2 & 7;
    const float* src = inw + (nt * 16 + lo) * 384 + 128 + h * 32 + lhi * 8;
#pragma unroll
    for (int j = 0; j < 8; ++j) v8[j] = src[j];
    dst = wsp + OFF_WK + t2 * 512 + l * 8;
  } else if (tt < 120) {
    // WV: t2 = (h*2+mt)*4+kt; src = inw[(kt*32+lhi*8+j)*384 + 256 + h*32
    //                                    + mt*16 + lo]
    const int t2 = tt - 88;
    const int kt = t2 & 3, q = t2 >> 2;
    const int h = q >> 1, mt = q & 1;
    const float* src =
        inw + (kt * 32 + lhi * 8) * 384 + 256 + h * 32 + mt * 16 + lo;
#pragma unroll
    for (int j = 0; j < 8; ++j) v8[j] = src[j * 384];
    dst = wsp + OFF_WV + t2 * 512 + l * 8;
  } else if (tt < 152) {
    // WO: t2 = nt*4+kt; src = outw[(kt*32+lhi*8+j)*128 + nt*16+lo]
    const int t2 = tt - 120;
    const int nt = t2 >> 2, kt = t2 & 3;
    const float* src = outw + (kt * 32 + lhi * 8) * 128 + nt * 16 + lo;
#pragma unroll
    for (int j = 0; j < 8; ++j) v8[j] = src[j * 128];
    dst = wsp + OFF_WO + t2 * 512 + l * 8;
  } else {
    // W2: t2 = nt*4+kt (nt<2); src = fc2w[(kt*32+lhi*8+j)*32 + nt*16+lo]
    const int t2 = tt - 152;
    const int nt = t2 >> 2, kt = t2 & 3;
    const float* src = fc2w + (kt * 32 + lhi * 8) * 32 + nt * 16 + lo;
#pragma unroll
    for (int j = 0; j < 8; ++j) v8[j] = src[j * 32];
    dst = wsp + OFF_W2 + t2 * 512 + l * 8;
  }
  bf16x8 o;
#pragma unroll
  for (int j = 0; j < 8; ++j) o[j] = (short)f2bf(v8[j]);
  *(bf16x8*)dst = o;
}

// LDS (bytes) — overlay map:
//   sx1 / vtbuf [128][136]bf16   0..34816   (x1, then V^T overlay rows h*32..)
//   sSlice 4x[16][136]           34816..52224  (per-wave transpose slices)
//     sattn [16][136] ALIASES sSlice+0     (live only after B2; slices dead)
//     sout  [16][136] ALIASES sSlice+4352  (live only after B3)
//   sres f32[32]                 52224..52352
//   sm   u8[128]                 52352..52480
// 52,480 B/block -> 3 blocks/CU resource limit (160KB/CU).
#define SMEM_BYTES 52480

__global__ __launch_bounds__(256, 2) void qmix_mfma(
    const float* __restrict__ agent_qs, const float* __restrict__ entities,
    const unsigned char* __restrict__ emask_g,
    const unsigned short* __restrict__ wsw, const int* __restrict__ mflag,
    const float* __restrict__ w_fc1b, const float* __restrict__ w_outb,
    const float* __restrict__ w_fc2b, const float* __restrict__ v_fc1b,
    const float* __restrict__ v_outb, const float* __restrict__ v_fc2b,
    float* __restrict__ out_g) {
  const int t = threadIdx.x;
  const int wv = t >> 6;  // wave == head
  const int ln = t & 63;
  const int lr = ln & 15;
  const int lq = ln >> 4;
  const int b = blockIdx.x;
  const float* ents = entities + (size_t)b * (NEn * EDm);

  __shared__ __align__(16) unsigned char smem[SMEM_BYTES];
  unsigned short* sx1 = (unsigned short*)smem;  // also vtbuf
  unsigned short* sSlice = sx1 + 17408;         // 4 slices
  unsigned short* sattn = sSlice;               // alias: live post-B2 only
  unsigned short* sout = sSlice + 16 * ST;      // alias: live post-B3 only
  float* sres = (float*)(smem + 52224);
  unsigned char* sm = smem + 52352;
  unsigned short* sS = sSlice + wv * 16 * ST;  // this wave's slice

  // ---- entity mask (dtype-normalized) ----
  const int is_i32 = *mflag;
  int mv = 1;
  if (t < NEn) {
    if (is_i32)
      mv = (((const int*)emask_g)[(size_t)b * NEn + t] != 0) ? 1 : 0;
    else
      mv = (emask_g[(size_t)b * NEn + t] != 0) ? 1 : 0;
    sm[t] = (unsigned char)mv;
  }
  const int allE = __syncthreads_and(mv);

  for (int p = 0; p < 2; ++p) {
    const unsigned short* wsb = wsw + (size_t)p * HYPE;
    const float* fc1b = p ? v_fc1b : w_fc1b;
    const float* outb = p ? v_outb : w_outb;
    const float* fc2b = p ? v_fc2b : w_fc2b;

    // ---- Phase A (co-op): x1 = relu(E @ W1 + b) -> sx1 [e][m] ----
    {
#pragma unroll
      for (int mi = 0; mi < 2; ++mi) {
        const int mt = wv * 2 + mi;
        bf16x8 af[3];
        const float* erow = ents + (mt * 16 + lr) * EDm + lq * 8;
#pragma unroll
        for (int kt = 0; kt < 3; ++kt) {
          float4 u = *(const float4*)(erow + kt * 32);
          float4 v = *(const float4*)(erow + kt * 32 + 4);
          bf16x8 a;
          a[0] = (short)f2bf(u.x); a[1] = (short)f2bf(u.y);
          a[2] = (short)f2bf(u.z); a[3] = (short)f2bf(u.w);
          a[4] = (short)f2bf(v.x); a[5] = (short)f2bf(v.y);
          a[6] = (short)f2bf(v.z); a[7] = (short)f2bf(v.w);
          af[kt] = a;
        }
        for (int nt = 0; nt < 8; ++nt) {
          f32x4 acc = {0.f, 0.f, 0.f, 0.f};
          const unsigned short* bp = wsb + OFF_W1 + (nt * 3) * 512 + ln * 8;
#pragma unroll
          for (int kt = 0; kt < 3; ++kt)
            acc = MFMA(af[kt], *(const bf16x8*)(bp + kt * 512), acc);
          const float bias = fc1b[nt * 16 + lr];
          f32x4 r;
          r[0] = fmaxf(acc[0] + bias, 0.f); r[1] = fmaxf(acc[1] + bias, 0.f);
          r[2] = fmaxf(acc[2] + bias, 0.f); r[3] = fmaxf(acc[3] + bias, 0.f);
          ctile_store(sx1, mt * 16 + lq * 4, nt * 16 + lr, r);
        }
      }
    }
    __syncthreads();  // B1: x1 complete (also fences prior sout/slice reads)

    // ---- Q (own head): Q_h[q][d] -> transpose via slice -> aQ ----
    {
      bf16x8 aq[4];
#pragma unroll
      for (int kt = 0; kt < 4; ++kt)
        aq[kt] = *(const bf16x8*)(sx1 + lr * ST + kt * 32 + lq * 8);
#pragma unroll
      for (int ni = 0; ni < 2; ++ni) {
        const int nt = wv * 2 + ni;
        f32x4 acc = {0.f, 0.f, 0.f, 0.f};
        const unsigned short* bp = wsb + OFF_WQ + (nt * 4) * 512 + ln * 8;
#pragma unroll
        for (int kt = 0; kt < 4; ++kt)
          acc = MFMA(aq[kt], *(const bf16x8*)(bp + kt * 512), acc);
        ctile_store(sS, lq * 4, ni * 16 + lr, acc);  // local d cols 0..31
      }
    }
    LGKM0();
    const bf16x8 aQ = *(const bf16x8*)(sS + lr * ST + lq * 8);  // A[q][d0..31]

    // ---- qW = Q_h @ Wk_h^T (8 m-tiles) -> transpose -> aw ----
    {
      f32x4 Cw[8];
#pragma unroll
      for (int nt = 0; nt < 8; ++nt) {
        f32x4 acc = {0.f, 0.f, 0.f, 0.f};
        Cw[nt] = MFMA(aQ, *(const bf16x8*)(wsb + OFF_WK + (wv * 8 + nt) * 512 +
                                           ln * 8),
                      acc);
      }
#pragma unroll
      for (int nt = 0; nt < 8; ++nt)
        ctile_store(sS, lq * 4, nt * 16 + lr, Cw[nt]);
    }
    LGKM0();
    bf16x8 aw[4];
#pragma unroll
    for (int kt = 0; kt < 4; ++kt)
      aw[kt] = *(const bf16x8*)(sS + lr * ST + kt * 32 + lq * 8);

    // ---- logits (full width, in-wave): Cl[nt] = qW @ x1^T ----
    f32x4 Cl[8];
#pragma unroll
    for (int nt = 0; nt < 8; ++nt) {
      f32x4 acc = {0.f, 0.f, 0.f, 0.f};
#pragma unroll
      for (int kt = 0; kt < 4; ++kt) {
        const bf16x8 bx =
            *(const bf16x8*)(sx1 + (nt * 16 + lr) * ST + kt * 32 + lq * 8);
        acc = MFMA(aw[kt], bx, acc);
      }
      Cl[nt] = acc;
    }

    // ---- in-wave softmax over 128 cols ----
    {
      float lv[8][4];
#pragma unroll
      for (int nt = 0; nt < 8; ++nt) {
        const int eM = sm[nt * 16 + lr];
#pragma unroll
        for (int r = 0; r < 4; ++r) lv[nt][r] = eM ? -1e9f : Cl[nt][r];
      }
      float mx[4], sl[4];
#pragma unroll
      for (int r = 0; r < 4; ++r) {
        float m = lv[0][r];
#pragma unroll
        for (int nt = 1; nt < 8; ++nt) m = fmaxf(m, lv[nt][r]);
        mx[r] = m;
      }
#pragma unroll
      for (int k = 1; k < 16; k <<= 1)
#pragma unroll
        for (int r = 0; r < 4; ++r) mx[r] = fmaxf(mx[r], __shfl_xor(mx[r], k));
      float ex[8][4];
#pragma unroll
      for (int r = 0; r < 4; ++r) sl[r] = 0.f;
#pragma unroll
      for (int nt = 0; nt < 8; ++nt)
#pragma unroll
        for (int r = 0; r < 4; ++r) {
          ex[nt][r] = __expf(lv[nt][r] - mx[r]);
          sl[r] += ex[nt][r];
        }
#pragma unroll
      for (int k = 1; k < 16; k <<= 1)
#pragma unroll
        for (int r = 0; r < 4; ++r) sl[r] += __shfl_xor(sl[r], k);
      float sc[4];
#pragma unroll
      for (int r = 0; r < 4; ++r)
        sc[r] = ((int)sm[lq * 4 + r] | allE) ? 0.f : (1.f / sl[r]);
#pragma unroll
      for (int nt = 0; nt < 8; ++nt) {
        f32x4 wv4;
#pragma unroll
        for (int r = 0; r < 4; ++r) wv4[r] = ex[nt][r] * sc[r];
        ctile_store(sS, lq * 4, nt * 16 + lr, wv4);  // W, overwrites qW
      }
    }
    LGKM0();
    bf16x8 aw2[4];
#pragma unroll
    for (int kt = 0; kt < 4; ++kt)
      aw2[kt] = *(const bf16x8*)(sS + lr * ST + kt * 32 + lq * 8);
    // sS (all slices) dead from here until next p's Q phase (post-next-B1).

    // ---- V^T_h = Wv_h^T @ x1^T into regs (x1 still live) ----
    f32x4 Cv[2][8];
#pragma unroll
    for (int mt = 0; mt < 2; ++mt) {
      bf16x8 av[4];
#pragma unroll
      for (int kt = 0; kt < 4; ++kt)
        av[kt] = *(const bf16x8*)(wsb + OFF_WV +
                                  (((wv * 2 + mt) * 4) + kt) * 512 + ln * 8);
#pragma unroll
      for (int nt = 0; nt < 8; ++nt) {
        f32x4 acc = {0.f, 0.f, 0.f, 0.f};
#pragma unroll
        for (int kt = 0; kt < 4; ++kt) {
          const bf16x8 bx =
              *(const bf16x8*)(sx1 + (nt * 16 + lr) * ST + kt * 32 + lq * 8);
          acc = MFMA(av[kt], bx, acc);
        }
        Cv[mt][nt] = acc;
      }
    }
    __syncthreads();  // B2: x1 dead -> vtbuf; slices dead -> sattn valid

    // ---- write V^T into own 32-row band of vtbuf; attn = W @ V_h ----
    {
#pragma unroll
      for (int mt = 0; mt < 2; ++mt)
#pragma unroll
        for (int nt = 0; nt < 8; ++nt)
          ctile_store(sx1, wv * 32 + mt * 16 + lq * 4, nt * 16 + lr,
                      Cv[mt][nt]);
    }
    LGKM0();
    {
#pragma unroll
      for (int ntd = 0; ntd < 2; ++ntd) {
        f32x4 acc = {0.f, 0.f, 0.f, 0.f};
#pragma unroll
        for (int kt = 0; kt < 4; ++kt) {
          const bf16x8 bv = *(const bf16x8*)(sx1 + (wv * 32 + ntd * 16 + lr) *
                                                       ST +
                                             kt * 32 + lq * 8);
          acc = MFMA(aw2[kt], bv, acc);
        }
        ctile_store(sattn, lq * 4, wv * 32 + ntd * 16 + lr, acc);
      }
    }
    __syncthreads();  // B3: sattn complete; sout region (slice 1) writable

    // ---- OUT = attn @ Wo + bo -> sout (co-op, 2 n-tiles/wave) ----
    {
      bf16x8 aa[4];
#pragma unroll
      for (int kt = 0; kt < 4; ++kt)
        aa[kt] = *(const bf16x8*)(sattn + lr * ST + kt * 32 + lq * 8);
#pragma unroll
      for (int ni = 0; ni < 2; ++ni) {
        const int nt = wv * 2 + ni;
        f32x4 acc = {0.f, 0.f, 0.f, 0.f};
        const unsigned short* bp = wsb + OFF_WO + (nt * 4) * 512 + ln * 8;
#pragma unroll
        for (int kt = 0; kt < 4; ++kt)
          acc = MFMA(aa[kt], *(const bf16x8*)(bp + kt * 512), acc);
        const float bj = outb[nt * 16 + lr];
        f32x4 r;
        r[0] = acc[0] + bj; r[1] = acc[1] + bj;
        r[2] = acc[2] + bj; r[3] = acc[3] + bj;
        ctile_store(sout, lq * 4, nt * 16 + lr, r);
      }
    }
    __syncthreads();  // B4: sout complete

    // ---- X3 = out @ fc2 + b (redundant per wave), mask, row-sum ----
    {
      bf16x8 ao[4];
#pragma unroll
      for (int kt = 0; kt < 4; ++kt)
        ao[kt] = *(const bf16x8*)(sout + lr * ST + kt * 32 + lq * 8);
      f32x4 Cx[2];
#pragma unroll
      for (int nt = 0; nt < 2; ++nt) {
        f32x4 acc = {0.f, 0.f, 0.f, 0.f};
        const unsigned short* bp = wsb + OFF_W2 + (nt * 4) * 512 + ln * 8;
#pragma unroll
        for (int kt = 0; kt < 4; ++kt)
          acc = MFMA(ao[kt], *(const bf16x8*)(bp + kt * 512), acc);
        Cx[nt] = acc;
      }
      const float b0 = fc2b[lr], b1 = fc2b[16 + lr];
      float rs[4];
#pragma unroll
      for (int r = 0; r < 4; ++r) {
        const int row = lq * 4 + r;
        rs[r] = sm[row] ? 0.f : (Cx[0][r] + b0 + Cx[1][r] + b1);
      }
#pragma unroll
      for (int k = 1; k < 16; k <<= 1)
#pragma unroll
        for (int r = 0; r < 4; ++r) rs[r] += __shfl_xor(rs[r], k);
      if (wv == 0 && lr == 0) {
#pragma unroll
        for (int r = 0; r < 4; ++r) {
          const int q = lq * 4 + r;
          sres[p * 16 + q] = p ? rs[r] : fabsf(rs[r]) * (1.f / 32.f);
        }
      }
    }
  }  // p

  __syncthreads();
  if (t == 0) {
    const float* qs = agent_qs + (size_t)b * NA;
    float tot = 0.f, vs = 0.f;
#pragma unroll
    for (int q = 0; q < NA; ++q) {
      tot += qs[q] * sres[q];
      vs += sres[16 + q];
    }
    out_g[b] = tot + vs * (1.f / 512.f);
  }
}

extern "C" void kernel_launch(void* const* d_in, const int* in_sizes, int n_in,
                              void* d_out, int out_size, void* d_ws,
                              size_t ws_size, hipStream_t stream) {
  (void)n_in; (void)out_size; (void)ws_size;
  const int nb = in_sizes[0] / NA;  // BS*T = 1600
  unsigned short* wsw = (unsigned short*)d_ws;
  int* mflag = (int*)((char*)d_ws + WS_FLAG_OFF);

  hipLaunchKernelGGL(prep_kernel, dim3(81), dim3(256), 0, stream,
                     (const float*)d_in[3], (const float*)d_in[5],
                     (const float*)d_in[6], (const float*)d_in[8],
                     (const float*)d_in[10], (const float*)d_in[12],
                     (const float*)d_in[13], (const float*)d_in[15],
                     (const unsigned char*)d_in[2], wsw, mflag);
  hipLaunchKernelGGL(qmix_mfma, dim3(nb), dim3(256), 0, stream,
                     (const float*)d_in[0], (const float*)d_in[1],
                     (const unsigned char*)d_in[2], (const unsigned short*)wsw,
                     (const int*)mflag, (const float*)d_in[4],
                     (const float*)d_in[7], (const float*)d_in[9],
                     (const float*)d_in[11], (const float*)d_in[14],
                     (const float*)d_in[16], (float*)d_out);
}

// Round 5
// 267.181 us; speedup vs baseline: 1.4083x; 1.0053x over previous
//
#include <hip/hip_runtime.h>

// LinearFlexQMixer MI355X — round 13: R12 NaN'd (5-change bundle; suspects
// are cvt_pk asm + deferred aw2 readback). Binary search: revert to R11's
// known-good memory schedule + manual f2bf, keep only the inert trio:
// (1) WK/WO/W2 global B-frag loads hoisted across preceding drain/barrier
// (pure global loads, no LDS-order change), (2) pragma unroll on Phase A nt
// loop, (3) s_setprio around logits/V^T MFMA clusters. cvt_pk and aw2
// deferral dropped — re-A/B next round if this lands clean.
// prep_kernel identical to R11.

#define NA 16
#define NEn 128
#define EDm 96
#define ST 136  // LDS row stride (shorts); 272B rows -> <=2-way conflicts

typedef __attribute__((ext_vector_type(8))) short bf16x8;
typedef __attribute__((ext_vector_type(4))) float f32x4;

#define MFMA(a, b, c) __builtin_amdgcn_mfma_f32_16x16x32_bf16((a), (b), (c), 0, 0, 0)
#define LGKM0() __asm__ volatile("s_waitcnt lgkmcnt(0)" ::: "memory")

// d_ws layout (bf16 elems), per hypernet p at p*HYPE:
#define OFF_W1 0       // [nt8][kt3][64][8]  B-frags Phase A (fc1w)
#define OFF_WQ 12288   // [nt8][kt4][64][8]  B-frags Q (inw cols 0:128, pre-scaled)
#define OFF_WK 28672   // [h4][nt8][64][8]   B-frags qW (Wk^T per head, K=32)
#define OFF_WV 45056   // [h4][mt2][kt4][64][8] A-frags V^T (Wv^T per head)
#define OFF_WO 61440   // [nt8][kt4][64][8]  B-frags OUT (outw)
#define OFF_W2 77824   // [nt2][kt4][64][8]  B-frags X3 (fc2w)
#define HYPE 81920
#define WS_FLAG_OFF 327680  // int flag: mask dtype (1 => int32)

__device__ __forceinline__ unsigned short f2bf(float f) {
  unsigned u = __float_as_uint(f);
  u += 0x7fffu + ((u >> 16) & 1u);  // RNE
  return (unsigned short)(u >> 16);
}

// Store one 16x16 C-tile column (4 f32, rows row0+0..3, col) as bf16 into
// LDS row-major [..][ST]. Pairs lanes (col, col^1) via shfl so every dword
// is written by exactly one lane. Full-wave calls only.
__device__ __forceinline__ void ctile_store(unsigned short* dst, int row0,
                                            int col, f32x4 v) {
  unsigned short m0 = f2bf(v[0]), m1 = f2bf(v[1]), m2 = f2bf(v[2]),
                 m3 = f2bf(v[3]);
  unsigned x = (unsigned)m0 | ((unsigned)m1 << 16);
  unsigned y = (unsigned)m2 | ((unsigned)m3 << 16);
  unsigned ox = (unsigned)__shfl_xor((int)x, 1);
  unsigned oy = (unsigned)__shfl_xor((int)y, 1);
  unsigned w0, w1;
  int ra;
  if ((threadIdx.x & 1) == 0) {
    ra = 0;
    w0 = (x & 0xffffu) | (ox << 16);
    w1 = (x >> 16) | (ox & 0xffff0000u);
  } else {
    ra = 2;
    w0 = (oy & 0xffffu) | (y << 16);
    w1 = (oy >> 16) | (y & 0xffff0000u);
  }
  *(unsigned*)(dst + (row0 + ra) * ST + (col & ~1)) = w0;
  *(unsigned*)(dst + (row0 + ra + 1) * ST + (col & ~1)) = w1;
}

// ---- prep (R11): destination-ordered gather. 80 work blocks + 1 mask blk.
__global__ void prep_kernel(const float* __restrict__ w_fc1w,
                            const float* __restrict__ w_inw,
                            const float* __restrict__ w_outw,
                            const float* __restrict__ w_fc2w,
                            const float* __restrict__ v_fc1w,
                            const float* __restrict__ v_inw,
                            const float* __restrict__ v_outw,
                            const float* __restrict__ v_fc2w,
                            const unsigned char* __restrict__ mask,
                            unsigned short* __restrict__ ws,
                            int* __restrict__ flag) {
  if (blockIdx.x == 80) {
    const uint4 v = *(const uint4*)(mask + threadIdx.x * 16);
    const unsigned nz = (v.x | v.y | v.z | v.w) & 0xffffff00u;
    const int any = __syncthreads_or((int)(nz != 0));
    if (threadIdx.x == 0) *flag = (any == 0) ? 1 : 0;
    return;
  }
  const int g = blockIdx.x * 256 + threadIdx.x;  // 0 .. 20479
  const int p = (g >= 10240) ? 1 : 0;
  const int i = g - p * 10240;
  const int l = i & 63;
  const int tt = i >> 6;  // 0..159
  const int lhi = l >> 4, lo = l & 15;
  const float* fc1w = p ? v_fc1w : w_fc1w;
  const float* inw = p ? v_inw : w_inw;
  const float* outw = p ? v_outw : w_outw;
  const float* fc2w = p ? v_fc2w : w_fc2w;
  unsigned short* wsp = ws + p * HYPE;

  float v8[8];
  unsigned short* dst;
  if (tt < 24) {
    const int nt = tt / 3, kt = tt - nt * 3;
    const float* src = fc1w + (kt * 32 + lhi * 8) * 128 + nt * 16 + lo;
#pragma unroll
    for (int j = 0; j < 8; ++j) v8[j] = src[j * 128];
    dst = wsp + OFF_W1 + tt * 512 + l * 8;
  } else if (tt < 56) {
    const int t2 = tt - 24;
    const int nt = t2 >> 2, kt = t2 & 3;
    const float* src = inw + (kt * 32 + lhi * 8) * 384 + nt * 16 + lo;
#pragma unroll
    for (int j = 0; j < 8; ++j) v8[j] = src[j * 384] * 0.17677669529663687f;
    dst = wsp + OFF_WQ + t2 * 512 + l * 8;
  } else if (tt < 88) {
    const int t2 = tt - 56;
    const int h = t2 >> 3, nt = t2 & 7;
    const float* src = inw + (nt * 16 + lo) * 384 + 128 + h * 32 + lhi * 8;
#pragma unroll
    for (int j = 0; j < 8; ++j) v8[j] = src[j];
    dst = wsp + OFF_WK + t2 * 512 + l * 8;
  } else if (tt < 120) {
    const int t2 = tt - 88;
    const int kt = t2 & 3, q = t2 >> 2;
    const int h = q >> 1, mt = q & 1;
    const float* src =
        inw + (kt * 32 + lhi * 8) * 384 + 256 + h * 32 + mt * 16 + lo;
#pragma unroll
    for (int j = 0; j < 8; ++j) v8[j] = src[j * 384];
    dst = wsp + OFF_WV + t2 * 512 + l * 8;
  } else if (tt < 152) {
    const int t2 = tt - 120;
    const int nt = t2 >> 2, kt = t2 & 3;
    const float* src = outw + (kt * 32 + lhi * 8) * 128 + nt * 16 + lo;
#pragma unroll
    for (int j = 0; j < 8; ++j) v8[j] = src[j * 128];
    dst = wsp + OFF_WO + t2 * 512 + l * 8;
  } else {
    const int t2 = tt - 152;
    const int nt = t2 >> 2, kt = t2 & 3;
    const float* src = fc2w + (kt * 32 + lhi * 8) * 32 + nt * 16 + lo;
#pragma unroll
    for (int j = 0; j < 8; ++j) v8[j] = src[j * 32];
    dst = wsp + OFF_W2 + t2 * 512 + l * 8;
  }
  bf16x8 o;
#pragma unroll
  for (int j = 0; j < 8; ++j) o[j] = (short)f2bf(v8[j]);
  *(bf16x8*)dst = o;
}

// LDS (bytes) — overlay map (unchanged from R10/R11):
//   sx1 / vtbuf [128][136]bf16   0..34816
//   sSlice 4x[16][136]           34816..52224  (per-wave transpose slices)
//     sattn ALIASES sSlice+0     (live post-B2 only; slices dead)
//     sout  ALIASES sSlice+4352  (live post-B3 only)
//   sres f32[32]                 52224..52352
//   sm   u8[128]                 52352..52480
// 52,480 B/block -> 3 blocks/CU resource limit (160KB/CU).
#define SMEM_BYTES 52480

__global__ __launch_bounds__(256, 2) void qmix_mfma(
    const float* __restrict__ agent_qs, const float* __restrict__ entities,
    const unsigned char* __restrict__ emask_g,
    const unsigned short* __restrict__ wsw, const int* __restrict__ mflag,
    const float* __restrict__ w_fc1b, const float* __restrict__ w_outb,
    const float* __restrict__ w_fc2b, const float* __restrict__ v_fc1b,
    const float* __restrict__ v_outb, const float* __restrict__ v_fc2b,
    float* __restrict__ out_g) {
  const int t = threadIdx.x;
  const int wv = t >> 6;  // wave == head
  const int ln = t & 63;
  const int lr = ln & 15;
  const int lq = ln >> 4;
  const int b = blockIdx.x;
  const float* ents = entities + (size_t)b * (NEn * EDm);

  __shared__ __align__(16) unsigned char smem[SMEM_BYTES];
  unsigned short* sx1 = (unsigned short*)smem;  // also vtbuf
  unsigned short* sSlice = sx1 + 17408;         // 4 slices
  unsigned short* sattn = sSlice;               // alias: live post-B2 only
  unsigned short* sout = sSlice + 16 * ST;      // alias: live post-B3 only
  float* sres = (float*)(smem + 52224);
  unsigned char* sm = smem + 52352;
  unsigned short* sS = sSlice + wv * 16 * ST;  // this wave's slice

  // ---- entity mask (dtype-normalized) ----
  const int is_i32 = *mflag;
  int mv = 1;
  if (t < NEn) {
    if (is_i32)
      mv = (((const int*)emask_g)[(size_t)b * NEn + t] != 0) ? 1 : 0;
    else
      mv = (emask_g[(size_t)b * NEn + t] != 0) ? 1 : 0;
    sm[t] = (unsigned char)mv;
  }
  const int allE = __syncthreads_and(mv);

  for (int p = 0; p < 2; ++p) {
    const unsigned short* wsb = wsw + (size_t)p * HYPE;
    const float* fc1b = p ? v_fc1b : w_fc1b;
    const float* outb = p ? v_outb : w_outb;
    const float* fc2b = p ? v_fc2b : w_fc2b;

    // ---- Phase A (co-op): x1 = relu(E @ W1 + b) -> sx1 [e][m] ----
    {
#pragma unroll
      for (int mi = 0; mi < 2; ++mi) {
        const int mt = wv * 2 + mi;
        bf16x8 af[3];
        const float* erow = ents + (mt * 16 + lr) * EDm + lq * 8;
#pragma unroll
        for (int kt = 0; kt < 3; ++kt) {
          float4 u = *(const float4*)(erow + kt * 32);
          float4 v = *(const float4*)(erow + kt * 32 + 4);
          bf16x8 a;
          a[0] = (short)f2bf(u.x); a[1] = (short)f2bf(u.y);
          a[2] = (short)f2bf(u.z); a[3] = (short)f2bf(u.w);
          a[4] = (short)f2bf(v.x); a[5] = (short)f2bf(v.y);
          a[6] = (short)f2bf(v.z); a[7] = (short)f2bf(v.w);
          af[kt] = a;
        }
#pragma unroll
        for (int nt = 0; nt < 8; ++nt) {
          f32x4 acc = {0.f, 0.f, 0.f, 0.f};
          const unsigned short* bp = wsb + OFF_W1 + (nt * 3) * 512 + ln * 8;
#pragma unroll
          for (int kt = 0; kt < 3; ++kt)
            acc = MFMA(af[kt], *(const bf16x8*)(bp + kt * 512), acc);
          const float bias = fc1b[nt * 16 + lr];
          f32x4 r;
          r[0] = fmaxf(acc[0] + bias, 0.f); r[1] = fmaxf(acc[1] + bias, 0.f);
          r[2] = fmaxf(acc[2] + bias, 0.f); r[3] = fmaxf(acc[3] + bias, 0.f);
          ctile_store(sx1, mt * 16 + lq * 4, nt * 16 + lr, r);
        }
      }
    }
    __syncthreads();  // B1: x1 complete (also fences prior sout/slice reads)

    // ---- Q (own head): Q_h[q][d] -> transpose via slice -> aQ ----
    {
      bf16x8 aq[4];
#pragma unroll
      for (int kt = 0; kt < 4; ++kt)
        aq[kt] = *(const bf16x8*)(sx1 + lr * ST + kt * 32 + lq * 8);
#pragma unroll
      for (int ni = 0; ni < 2; ++ni) {
        const int nt = wv * 2 + ni;
        f32x4 acc = {0.f, 0.f, 0.f, 0.f};
        const unsigned short* bp = wsb + OFF_WQ + (nt * 4) * 512 + ln * 8;
#pragma unroll
        for (int kt = 0; kt < 4; ++kt)
          acc = MFMA(aq[kt], *(const bf16x8*)(bp + kt * 512), acc);
        ctile_store(sS, lq * 4, ni * 16 + lr, acc);  // local d cols 0..31
      }
    }
    // hoist qW's global WK B-frags above the transpose drain (independent)
    bf16x8 wk[8];
#pragma unroll
    for (int nt = 0; nt < 8; ++nt)
      wk[nt] =
          *(const bf16x8*)(wsb + OFF_WK + (wv * 8 + nt) * 512 + ln * 8);
    LGKM0();
    const bf16x8 aQ = *(const bf16x8*)(sS + lr * ST + lq * 8);  // A[q][d0..31]

    // ---- qW = Q_h @ Wk_h^T (8 m-tiles) -> transpose -> aw ----
    {
      f32x4 Cw[8];
#pragma unroll
      for (int nt = 0; nt < 8; ++nt) {
        f32x4 acc = {0.f, 0.f, 0.f, 0.f};
        Cw[nt] = MFMA(aQ, wk[nt], acc);
      }
#pragma unroll
      for (int nt = 0; nt < 8; ++nt)
        ctile_store(sS, lq * 4, nt * 16 + lr, Cw[nt]);
    }
    LGKM0();
    bf16x8 aw[4];
#pragma unroll
    for (int kt = 0; kt < 4; ++kt)
      aw[kt] = *(const bf16x8*)(sS + lr * ST + kt * 32 + lq * 8);

    // ---- logits (full width, in-wave): Cl[nt] = qW @ x1^T ----
    f32x4 Cl[8];
    __builtin_amdgcn_s_setprio(1);
#pragma unroll
    for (int nt = 0; nt < 8; ++nt) {
      f32x4 acc = {0.f, 0.f, 0.f, 0.f};
#pragma unroll
      for (int kt = 0; kt < 4; ++kt) {
        const bf16x8 bx =
            *(const bf16x8*)(sx1 + (nt * 16 + lr) * ST + kt * 32 + lq * 8);
        acc = MFMA(aw[kt], bx, acc);
      }
      Cl[nt] = acc;
    }
    __builtin_amdgcn_s_setprio(0);

    // ---- in-wave softmax over 128 cols ----
    {
      float lv[8][4];
#pragma unroll
      for (int nt = 0; nt < 8; ++nt) {
        const int eM = sm[nt * 16 + lr];
#pragma unroll
        for (int r = 0; r < 4; ++r) lv[nt][r] = eM ? -1e9f : Cl[nt][r];
      }
      float mx[4], sl[4];
#pragma unroll
      for (int r = 0; r < 4; ++r) {
        float m = lv[0][r];
#pragma unroll
        for (int nt = 1; nt < 8; ++nt) m = fmaxf(m, lv[nt][r]);
        mx[r] = m;
      }
#pragma unroll
      for (int k = 1; k < 16; k <<= 1)
#pragma unroll
        for (int r = 0; r < 4; ++r) mx[r] = fmaxf(mx[r], __shfl_xor(mx[r], k));
      float ex[8][4];
#pragma unroll
      for (int r = 0; r < 4; ++r) sl[r] = 0.f;
#pragma unroll
      for (int nt = 0; nt < 8; ++nt)
#pragma unroll
        for (int r = 0; r < 4; ++r) {
          ex[nt][r] = __expf(lv[nt][r] - mx[r]);
          sl[r] += ex[nt][r];
        }
#pragma unroll
      for (int k = 1; k < 16; k <<= 1)
#pragma unroll
        for (int r = 0; r < 4; ++r) sl[r] += __shfl_xor(sl[r], k);
      float sc[4];
#pragma unroll
      for (int r = 0; r < 4; ++r)
        sc[r] = ((int)sm[lq * 4 + r] | allE) ? 0.f : (1.f / sl[r]);
#pragma unroll
      for (int nt = 0; nt < 8; ++nt) {
        f32x4 wv4;
#pragma unroll
        for (int r = 0; r < 4; ++r) wv4[r] = ex[nt][r] * sc[r];
        ctile_store(sS, lq * 4, nt * 16 + lr, wv4);  // W, overwrites qW
      }
    }
    LGKM0();
    bf16x8 aw2[4];
#pragma unroll
    for (int kt = 0; kt < 4; ++kt)
      aw2[kt] = *(const bf16x8*)(sS + lr * ST + kt * 32 + lq * 8);
    // sS (all slices) dead from here until next p's Q phase (post-next-B1).

    // ---- V^T_h = Wv_h^T @ x1^T into regs (x1 still live) ----
    f32x4 Cv[2][8];
    __builtin_amdgcn_s_setprio(1);
#pragma unroll
    for (int mt = 0; mt < 2; ++mt) {
      bf16x8 av[4];
#pragma unroll
      for (int kt = 0; kt < 4; ++kt)
        av[kt] = *(const bf16x8*)(wsb + OFF_WV +
                                  (((wv * 2 + mt) * 4) + kt) * 512 + ln * 8);
#pragma unroll
      for (int nt = 0; nt < 8; ++nt) {
        f32x4 acc = {0.f, 0.f, 0.f, 0.f};
#pragma unroll
        for (int kt = 0; kt < 4; ++kt) {
          const bf16x8 bx =
              *(const bf16x8*)(sx1 + (nt * 16 + lr) * ST + kt * 32 + lq * 8);
          acc = MFMA(av[kt], bx, acc);
        }
        Cv[mt][nt] = acc;
      }
    }
    __builtin_amdgcn_s_setprio(0);
    __syncthreads();  // B2: x1 dead -> vtbuf; slices dead -> sattn valid

    // ---- write V^T into own 32-row band of vtbuf; attn = W @ V_h ----
    {
#pragma unroll
      for (int mt = 0; mt < 2; ++mt)
#pragma unroll
        for (int nt = 0; nt < 8; ++nt)
          ctile_store(sx1, wv * 32 + mt * 16 + lq * 4, nt * 16 + lr,
                      Cv[mt][nt]);
    }
    LGKM0();
    {
#pragma unroll
      for (int ntd = 0; ntd < 2; ++ntd) {
        f32x4 acc = {0.f, 0.f, 0.f, 0.f};
#pragma unroll
        for (int kt = 0; kt < 4; ++kt) {
          const bf16x8 bv = *(const bf16x8*)(sx1 + (wv * 32 + ntd * 16 + lr) *
                                                       ST +
                                             kt * 32 + lq * 8);
          acc = MFMA(aw2[kt], bv, acc);
        }
        ctile_store(sattn, lq * 4, wv * 32 + ntd * 16 + lr, acc);
      }
    }
    // hoist OUT's WO B-frags across B3 (independent of sattn)
    bf16x8 wo[2][4];
#pragma unroll
    for (int ni = 0; ni < 2; ++ni) {
      const unsigned short* bp =
          wsb + OFF_WO + ((wv * 2 + ni) * 4) * 512 + ln * 8;
#pragma unroll
      for (int kt = 0; kt < 4; ++kt)
        wo[ni][kt] = *(const bf16x8*)(bp + kt * 512);
    }
    __syncthreads();  // B3: sattn complete; sout region (slice 1) writable

    // ---- OUT = attn @ Wo + bo -> sout (co-op, 2 n-tiles/wave) ----
    {
      bf16x8 aa[4];
#pragma unroll
      for (int kt = 0; kt < 4; ++kt)
        aa[kt] = *(const bf16x8*)(sattn + lr * ST + kt * 32 + lq * 8);
#pragma unroll
      for (int ni = 0; ni < 2; ++ni) {
        const int nt = wv * 2 + ni;
        f32x4 acc = {0.f, 0.f, 0.f, 0.f};
#pragma unroll
        for (int kt = 0; kt < 4; ++kt)
          acc = MFMA(aa[kt], wo[ni][kt], acc);
        const float bj = outb[nt * 16 + lr];
        f32x4 r;
        r[0] = acc[0] + bj; r[1] = acc[1] + bj;
        r[2] = acc[2] + bj; r[3] = acc[3] + bj;
        ctile_store(sout, lq * 4, nt * 16 + lr, r);
      }
    }
    // hoist X3's W2 B-frags across B4 (independent of sout)
    bf16x8 w2f[2][4];
#pragma unroll
    for (int nt = 0; nt < 2; ++nt) {
      const unsigned short* bp = wsb + OFF_W2 + (nt * 4) * 512 + ln * 8;
#pragma unroll
      for (int kt = 0; kt < 4; ++kt)
        w2f[nt][kt] = *(const bf16x8*)(bp + kt * 512);
    }
    __syncthreads();  // B4: sout complete

    // ---- X3 = out @ fc2 + b (redundant per wave), mask, row-sum ----
    {
      bf16x8 ao[4];
#pragma unroll
      for (int kt = 0; kt < 4; ++kt)
        ao[kt] = *(const bf16x8*)(sout + lr * ST + kt * 32 + lq * 8);
      f32x4 Cx[2];
#pragma unroll
      for (int nt = 0; nt < 2; ++nt) {
        f32x4 acc = {0.f, 0.f, 0.f, 0.f};
#pragma unroll
        for (int kt = 0; kt < 4; ++kt)
          acc = MFMA(ao[kt], w2f[nt][kt], acc);
        Cx[nt] = acc;
      }
      const float b0 = fc2b[lr], b1 = fc2b[16 + lr];
      float rs[4];
#pragma unroll
      for (int r = 0; r < 4; ++r) {
        const int row = lq * 4 + r;
        rs[r] = sm[row] ? 0.f : (Cx[0][r] + b0 + Cx[1][r] + b1);
      }
#pragma unroll
      for (int k = 1; k < 16; k <<= 1)
#pragma unroll
        for (int r = 0; r < 4; ++r) rs[r] += __shfl_xor(rs[r], k);
      if (wv == 0 && lr == 0) {
#pragma unroll
        for (int r = 0; r < 4; ++r) {
          const int q = lq * 4 + r;
          sres[p * 16 + q] = p ? rs[r] : fabsf(rs[r]) * (1.f / 32.f);
        }
      }
    }
  }  // p

  __syncthreads();
  if (t == 0) {
    const float* qs = agent_qs + (size_t)b * NA;
    float tot = 0.f, vs = 0.f;
#pragma unroll
    for (int q = 0; q < NA; ++q) {
      tot += qs[q] * sres[q];
      vs += sres[16 + q];
    }
    out_g[b] = tot + vs * (1.f / 512.f);
  }
}

extern "C" void kernel_launch(void* const* d_in, const int* in_sizes, int n_in,
                              void* d_out, int out_size, void* d_ws,
                              size_t ws_size, hipStream_t stream) {
  (void)n_in; (void)out_size; (void)ws_size;
  const int nb = in_sizes[0] / NA;  // BS*T = 1600
  unsigned short* wsw = (unsigned short*)d_ws;
  int* mflag = (int*)((char*)d_ws + WS_FLAG_OFF);

  hipLaunchKernelGGL(prep_kernel, dim3(81), dim3(256), 0, stream,
                     (const float*)d_in[3], (const float*)d_in[5],
                     (const float*)d_in[6], (const float*)d_in[8],
                     (const float*)d_in[10], (const float*)d_in[12],
                     (const float*)d_in[13], (const float*)d_in[15],
                     (const unsigned char*)d_in[2], wsw, mflag);
  hipLaunchKernelGGL(qmix_mfma, dim3(nb), dim3(256), 0, stream,
                     (const float*)d_in[0], (const float*)d_in[1],
                     (const unsigned char*)d_in[2], (const unsigned short*)wsw,
                     (const int*)mflag, (const float*)d_in[4],
                     (const float*)d_in[7], (const float*)d_in[9],
                     (const float*)d_in[11], (const float*)d_in[14],
                     (const float*)d_in[16], (float*)d_out);
}

// Round 6
// 252.406 us; speedup vs baseline: 1.4907x; 1.0585x over previous
//
#include <hip/hip_runtime.h>

// LinearFlexQMixer MI355X — round 14: p-split across blocks (grid 2x).
// R13 post-mortem: scheduling tweaks neutral; bench = qmix + ~111us harness
// reset (fixed). Block wall ~75us for ~6us of work; 1600 blocks / 768
// resident slots = 2.08 rounds -> tail runs at <8% occupancy for up to a
// block-length (~25-35us of the 156). The two hypernets (p=0/1) are fully
// independent chains (Phase A is per-p; E re-read per p already). Split:
// grid 3200, block = one p-chain (half serial length, half tail quantum),
// combine via 2 atomicAdds/b into the harness-zeroed output (2 addends,
// order-independent -> deterministic). Phase code + LDS layout byte-identical
// to R13. prep_kernel unchanged.

#define NA 16
#define NEn 128
#define EDm 96
#define ST 136  // LDS row stride (shorts); 272B rows -> <=2-way conflicts

typedef __attribute__((ext_vector_type(8))) short bf16x8;
typedef __attribute__((ext_vector_type(4))) float f32x4;

#define MFMA(a, b, c) __builtin_amdgcn_mfma_f32_16x16x32_bf16((a), (b), (c), 0, 0, 0)
#define LGKM0() __asm__ volatile("s_waitcnt lgkmcnt(0)" ::: "memory")

// d_ws layout (bf16 elems), per hypernet p at p*HYPE:
#define OFF_W1 0       // [nt8][kt3][64][8]  B-frags Phase A (fc1w)
#define OFF_WQ 12288   // [nt8][kt4][64][8]  B-frags Q (inw cols 0:128, pre-scaled)
#define OFF_WK 28672   // [h4][nt8][64][8]   B-frags qW (Wk^T per head, K=32)
#define OFF_WV 45056   // [h4][mt2][kt4][64][8] A-frags V^T (Wv^T per head)
#define OFF_WO 61440   // [nt8][kt4][64][8]  B-frags OUT (outw)
#define OFF_W2 77824   // [nt2][kt4][64][8]  B-frags X3 (fc2w)
#define HYPE 81920
#define WS_FLAG_OFF 327680  // int flag: mask dtype (1 => int32)

__device__ __forceinline__ unsigned short f2bf(float f) {
  unsigned u = __float_as_uint(f);
  u += 0x7fffu + ((u >> 16) & 1u);  // RNE
  return (unsigned short)(u >> 16);
}

// Store one 16x16 C-tile column (4 f32, rows row0+0..3, col) as bf16 into
// LDS row-major [..][ST]. Pairs lanes (col, col^1) via shfl so every dword
// is written by exactly one lane. Full-wave calls only.
__device__ __forceinline__ void ctile_store(unsigned short* dst, int row0,
                                            int col, f32x4 v) {
  unsigned short m0 = f2bf(v[0]), m1 = f2bf(v[1]), m2 = f2bf(v[2]),
                 m3 = f2bf(v[3]);
  unsigned x = (unsigned)m0 | ((unsigned)m1 << 16);
  unsigned y = (unsigned)m2 | ((unsigned)m3 << 16);
  unsigned ox = (unsigned)__shfl_xor((int)x, 1);
  unsigned oy = (unsigned)__shfl_xor((int)y, 1);
  unsigned w0, w1;
  int ra;
  if ((threadIdx.x & 1) == 0) {
    ra = 0;
    w0 = (x & 0xffffu) | (ox << 16);
    w1 = (x >> 16) | (ox & 0xffff0000u);
  } else {
    ra = 2;
    w0 = (oy & 0xffffu) | (y << 16);
    w1 = (oy >> 16) | (y & 0xffff0000u);
  }
  *(unsigned*)(dst + (row0 + ra) * ST + (col & ~1)) = w0;
  *(unsigned*)(dst + (row0 + ra + 1) * ST + (col & ~1)) = w1;
}

// ---- prep (R11): destination-ordered gather. 80 work blocks + 1 mask blk.
__global__ void prep_kernel(const float* __restrict__ w_fc1w,
                            const float* __restrict__ w_inw,
                            const float* __restrict__ w_outw,
                            const float* __restrict__ w_fc2w,
                            const float* __restrict__ v_fc1w,
                            const float* __restrict__ v_inw,
                            const float* __restrict__ v_outw,
                            const float* __restrict__ v_fc2w,
                            const unsigned char* __restrict__ mask,
                            unsigned short* __restrict__ ws,
                            int* __restrict__ flag) {
  if (blockIdx.x == 80) {
    const uint4 v = *(const uint4*)(mask + threadIdx.x * 16);
    const unsigned nz = (v.x | v.y | v.z | v.w) & 0xffffff00u;
    const int any = __syncthreads_or((int)(nz != 0));
    if (threadIdx.x == 0) *flag = (any == 0) ? 1 : 0;
    return;
  }
  const int g = blockIdx.x * 256 + threadIdx.x;  // 0 .. 20479
  const int p = (g >= 10240) ? 1 : 0;
  const int i = g - p * 10240;
  const int l = i & 63;
  const int tt = i >> 6;  // 0..159
  const int lhi = l >> 4, lo = l & 15;
  const float* fc1w = p ? v_fc1w : w_fc1w;
  const float* inw = p ? v_inw : w_inw;
  const float* outw = p ? v_outw : w_outw;
  const float* fc2w = p ? v_fc2w : w_fc2w;
  unsigned short* wsp = ws + p * HYPE;

  float v8[8];
  unsigned short* dst;
  if (tt < 24) {
    const int nt = tt / 3, kt = tt - nt * 3;
    const float* src = fc1w + (kt * 32 + lhi * 8) * 128 + nt * 16 + lo;
#pragma unroll
    for (int j = 0; j < 8; ++j) v8[j] = src[j * 128];
    dst = wsp + OFF_W1 + tt * 512 + l * 8;
  } else if (tt < 56) {
    const int t2 = tt - 24;
    const int nt = t2 >> 2, kt = t2 & 3;
    const float* src = inw + (kt * 32 + lhi * 8) * 384 + nt * 16 + lo;
#pragma unroll
    for (int j = 0; j < 8; ++j) v8[j] = src[j * 384] * 0.17677669529663687f;
    dst = wsp + OFF_WQ + t2 * 512 + l * 8;
  } else if (tt < 88) {
    const int t2 = tt - 56;
    const int h = t2 >> 3, nt = t2 & 7;
    const float* src = inw + (nt * 16 + lo) * 384 + 128 + h * 32 + lhi * 8;
#pragma unroll
    for (int j = 0; j < 8; ++j) v8[j] = src[j];
    dst = wsp + OFF_WK + t2 * 512 + l * 8;
  } else if (tt < 120) {
    const int t2 = tt - 88;
    const int kt = t2 & 3, q = t2 >> 2;
    const int h = q >> 1, mt = q & 1;
    const float* src =
        inw + (kt * 32 + lhi * 8) * 384 + 256 + h * 32 + mt * 16 + lo;
#pragma unroll
    for (int j = 0; j < 8; ++j) v8[j] = src[j * 384];
    dst = wsp + OFF_WV + t2 * 512 + l * 8;
  } else if (tt < 152) {
    const int t2 = tt - 120;
    const int nt = t2 >> 2, kt = t2 & 3;
    const float* src = outw + (kt * 32 + lhi * 8) * 128 + nt * 16 + lo;
#pragma unroll
    for (int j = 0; j < 8; ++j) v8[j] = src[j * 128];
    dst = wsp + OFF_WO + t2 * 512 + l * 8;
  } else {
    const int t2 = tt - 152;
    const int nt = t2 >> 2, kt = t2 & 3;
    const float* src = fc2w + (kt * 32 + lhi * 8) * 32 + nt * 16 + lo;
#pragma unroll
    for (int j = 0; j < 8; ++j) v8[j] = src[j * 32];
    dst = wsp + OFF_W2 + t2 * 512 + l * 8;
  }
  bf16x8 o;
#pragma unroll
  for (int j = 0; j < 8; ++j) o[j] = (short)f2bf(v8[j]);
  *(bf16x8*)dst = o;
}

// LDS (bytes) — overlay map (unchanged from R10..R13):
//   sx1 / vtbuf [128][136]bf16   0..34816
//   sSlice 4x[16][136]           34816..52224  (per-wave transpose slices)
//     sattn ALIASES sSlice+0     (live post-B2 only; slices dead)
//     sout  ALIASES sSlice+4352  (live post-B3 only)
//   sres f32[32]                 52224..52352  (only [0..15] used now)
//   sm   u8[128]                 52352..52480
// 52,480 B/block -> 3 blocks/CU resource limit (160KB/CU).
#define SMEM_BYTES 52480

__global__ __launch_bounds__(256, 2) void qmix_mfma(
    const float* __restrict__ agent_qs, const float* __restrict__ entities,
    const unsigned char* __restrict__ emask_g,
    const unsigned short* __restrict__ wsw, const int* __restrict__ mflag,
    const float* __restrict__ w_fc1b, const float* __restrict__ w_outb,
    const float* __restrict__ w_fc2b, const float* __restrict__ v_fc1b,
    const float* __restrict__ v_outb, const float* __restrict__ v_fc2b,
    float* __restrict__ out_g) {
  const int t = threadIdx.x;
  const int wv = t >> 6;  // wave == head
  const int ln = t & 63;
  const int lr = ln & 15;
  const int lq = ln >> 4;
  const int b = blockIdx.x >> 1;   // batch element
  const int p = blockIdx.x & 1;    // hypernet (0: w1, 1: v)
  const float* ents = entities + (size_t)b * (NEn * EDm);

  __shared__ __align__(16) unsigned char smem[SMEM_BYTES];
  unsigned short* sx1 = (unsigned short*)smem;  // also vtbuf
  unsigned short* sSlice = sx1 + 17408;         // 4 slices
  unsigned short* sattn = sSlice;               // alias: live post-B2 only
  unsigned short* sout = sSlice + 16 * ST;      // alias: live post-B3 only
  float* sres = (float*)(smem + 52224);
  unsigned char* sm = smem + 52352;
  unsigned short* sS = sSlice + wv * 16 * ST;  // this wave's slice

  // ---- entity mask (dtype-normalized) ----
  const int is_i32 = *mflag;
  int mv = 1;
  if (t < NEn) {
    if (is_i32)
      mv = (((const int*)emask_g)[(size_t)b * NEn + t] != 0) ? 1 : 0;
    else
      mv = (emask_g[(size_t)b * NEn + t] != 0) ? 1 : 0;
    sm[t] = (unsigned char)mv;
  }
  const int allE = __syncthreads_and(mv);

  const unsigned short* wsb = wsw + (size_t)p * HYPE;
  const float* fc1b = p ? v_fc1b : w_fc1b;
  const float* outb = p ? v_outb : w_outb;
  const float* fc2b = p ? v_fc2b : w_fc2b;

  // ---- Phase A (co-op): x1 = relu(E @ W1 + b) -> sx1 [e][m] ----
  {
#pragma unroll
    for (int mi = 0; mi < 2; ++mi) {
      const int mt = wv * 2 + mi;
      bf16x8 af[3];
      const float* erow = ents + (mt * 16 + lr) * EDm + lq * 8;
#pragma unroll
      for (int kt = 0; kt < 3; ++kt) {
        float4 u = *(const float4*)(erow + kt * 32);
        float4 v = *(const float4*)(erow + kt * 32 + 4);
        bf16x8 a;
        a[0] = (short)f2bf(u.x); a[1] = (short)f2bf(u.y);
        a[2] = (short)f2bf(u.z); a[3] = (short)f2bf(u.w);
        a[4] = (short)f2bf(v.x); a[5] = (short)f2bf(v.y);
        a[6] = (short)f2bf(v.z); a[7] = (short)f2bf(v.w);
        af[kt] = a;
      }
#pragma unroll
      for (int nt = 0; nt < 8; ++nt) {
        f32x4 acc = {0.f, 0.f, 0.f, 0.f};
        const unsigned short* bp = wsb + OFF_W1 + (nt * 3) * 512 + ln * 8;
#pragma unroll
        for (int kt = 0; kt < 3; ++kt)
          acc = MFMA(af[kt], *(const bf16x8*)(bp + kt * 512), acc);
        const float bias = fc1b[nt * 16 + lr];
        f32x4 r;
        r[0] = fmaxf(acc[0] + bias, 0.f); r[1] = fmaxf(acc[1] + bias, 0.f);
        r[2] = fmaxf(acc[2] + bias, 0.f); r[3] = fmaxf(acc[3] + bias, 0.f);
        ctile_store(sx1, mt * 16 + lq * 4, nt * 16 + lr, r);
      }
    }
  }
  __syncthreads();  // B1: x1 complete

  // ---- Q (own head): Q_h[q][d] -> transpose via slice -> aQ ----
  {
    bf16x8 aq[4];
#pragma unroll
    for (int kt = 0; kt < 4; ++kt)
      aq[kt] = *(const bf16x8*)(sx1 + lr * ST + kt * 32 + lq * 8);
#pragma unroll
    for (int ni = 0; ni < 2; ++ni) {
      const int nt = wv * 2 + ni;
      f32x4 acc = {0.f, 0.f, 0.f, 0.f};
      const unsigned short* bp = wsb + OFF_WQ + (nt * 4) * 512 + ln * 8;
#pragma unroll
      for (int kt = 0; kt < 4; ++kt)
        acc = MFMA(aq[kt], *(const bf16x8*)(bp + kt * 512), acc);
      ctile_store(sS, lq * 4, ni * 16 + lr, acc);  // local d cols 0..31
    }
  }
  // hoist qW's global WK B-frags above the transpose drain (independent)
  bf16x8 wk[8];
#pragma unroll
  for (int nt = 0; nt < 8; ++nt)
    wk[nt] = *(const bf16x8*)(wsb + OFF_WK + (wv * 8 + nt) * 512 + ln * 8);
  LGKM0();
  const bf16x8 aQ = *(const bf16x8*)(sS + lr * ST + lq * 8);  // A[q][d0..31]

  // ---- qW = Q_h @ Wk_h^T (8 m-tiles) -> transpose -> aw ----
  {
    f32x4 Cw[8];
#pragma unroll
    for (int nt = 0; nt < 8; ++nt) {
      f32x4 acc = {0.f, 0.f, 0.f, 0.f};
      Cw[nt] = MFMA(aQ, wk[nt], acc);
    }
#pragma unroll
    for (int nt = 0; nt < 8; ++nt)
      ctile_store(sS, lq * 4, nt * 16 + lr, Cw[nt]);
  }
  LGKM0();
  bf16x8 aw[4];
#pragma unroll
  for (int kt = 0; kt < 4; ++kt)
    aw[kt] = *(const bf16x8*)(sS + lr * ST + kt * 32 + lq * 8);

  // ---- logits (full width, in-wave): Cl[nt] = qW @ x1^T ----
  f32x4 Cl[8];
  __builtin_amdgcn_s_setprio(1);
#pragma unroll
  for (int nt = 0; nt < 8; ++nt) {
    f32x4 acc = {0.f, 0.f, 0.f, 0.f};
#pragma unroll
    for (int kt = 0; kt < 4; ++kt) {
      const bf16x8 bx =
          *(const bf16x8*)(sx1 + (nt * 16 + lr) * ST + kt * 32 + lq * 8);
      acc = MFMA(aw[kt], bx, acc);
    }
    Cl[nt] = acc;
  }
  __builtin_amdgcn_s_setprio(0);

  // ---- in-wave softmax over 128 cols ----
  {
    float lv[8][4];
#pragma unroll
    for (int nt = 0; nt < 8; ++nt) {
      const int eM = sm[nt * 16 + lr];
#pragma unroll
      for (int r = 0; r < 4; ++r) lv[nt][r] = eM ? -1e9f : Cl[nt][r];
    }
    float mx[4], sl[4];
#pragma unroll
    for (int r = 0; r < 4; ++r) {
      float m = lv[0][r];
#pragma unroll
      for (int nt = 1; nt < 8; ++nt) m = fmaxf(m, lv[nt][r]);
      mx[r] = m;
    }
#pragma unroll
    for (int k = 1; k < 16; k <<= 1)
#pragma unroll
      for (int r = 0; r < 4; ++r) mx[r] = fmaxf(mx[r], __shfl_xor(mx[r], k));
    float ex[8][4];
#pragma unroll
    for (int r = 0; r < 4; ++r) sl[r] = 0.f;
#pragma unroll
    for (int nt = 0; nt < 8; ++nt)
#pragma unroll
      for (int r = 0; r < 4; ++r) {
        ex[nt][r] = __expf(lv[nt][r] - mx[r]);
        sl[r] += ex[nt][r];
      }
#pragma unroll
    for (int k = 1; k < 16; k <<= 1)
#pragma unroll
      for (int r = 0; r < 4; ++r) sl[r] += __shfl_xor(sl[r], k);
    float sc[4];
#pragma unroll
    for (int r = 0; r < 4; ++r)
      sc[r] = ((int)sm[lq * 4 + r] | allE) ? 0.f : (1.f / sl[r]);
#pragma unroll
    for (int nt = 0; nt < 8; ++nt) {
      f32x4 wv4;
#pragma unroll
      for (int r = 0; r < 4; ++r) wv4[r] = ex[nt][r] * sc[r];
      ctile_store(sS, lq * 4, nt * 16 + lr, wv4);  // W, overwrites qW
    }
  }
  LGKM0();
  bf16x8 aw2[4];
#pragma unroll
  for (int kt = 0; kt < 4; ++kt)
    aw2[kt] = *(const bf16x8*)(sS + lr * ST + kt * 32 + lq * 8);
  // sS (all slices) dead from here on.

  // ---- V^T_h = Wv_h^T @ x1^T into regs (x1 still live) ----
  f32x4 Cv[2][8];
  __builtin_amdgcn_s_setprio(1);
#pragma unroll
  for (int mt = 0; mt < 2; ++mt) {
    bf16x8 av[4];
#pragma unroll
    for (int kt = 0; kt < 4; ++kt)
      av[kt] = *(const bf16x8*)(wsb + OFF_WV +
                                (((wv * 2 + mt) * 4) + kt) * 512 + ln * 8);
#pragma unroll
    for (int nt = 0; nt < 8; ++nt) {
      f32x4 acc = {0.f, 0.f, 0.f, 0.f};
#pragma unroll
      for (int kt = 0; kt < 4; ++kt) {
        const bf16x8 bx =
            *(const bf16x8*)(sx1 + (nt * 16 + lr) * ST + kt * 32 + lq * 8);
        acc = MFMA(av[kt], bx, acc);
      }
      Cv[mt][nt] = acc;
    }
  }
  __builtin_amdgcn_s_setprio(0);
  __syncthreads();  // B2: x1 dead -> vtbuf; slices dead -> sattn valid

  // ---- write V^T into own 32-row band of vtbuf; attn = W @ V_h ----
  {
#pragma unroll
    for (int mt = 0; mt < 2; ++mt)
#pragma unroll
      for (int nt = 0; nt < 8; ++nt)
        ctile_store(sx1, wv * 32 + mt * 16 + lq * 4, nt * 16 + lr,
                    Cv[mt][nt]);
  }
  LGKM0();
  {
#pragma unroll
    for (int ntd = 0; ntd < 2; ++ntd) {
      f32x4 acc = {0.f, 0.f, 0.f, 0.f};
#pragma unroll
      for (int kt = 0; kt < 4; ++kt) {
        const bf16x8 bv = *(const bf16x8*)(sx1 + (wv * 32 + ntd * 16 + lr) *
                                                     ST +
                                           kt * 32 + lq * 8);
        acc = MFMA(aw2[kt], bv, acc);
      }
      ctile_store(sattn, lq * 4, wv * 32 + ntd * 16 + lr, acc);
    }
  }
  // hoist OUT's WO B-frags across B3 (independent of sattn)
  bf16x8 wo[2][4];
#pragma unroll
  for (int ni = 0; ni < 2; ++ni) {
    const unsigned short* bp =
        wsb + OFF_WO + ((wv * 2 + ni) * 4) * 512 + ln * 8;
#pragma unroll
    for (int kt = 0; kt < 4; ++kt)
      wo[ni][kt] = *(const bf16x8*)(bp + kt * 512);
  }
  __syncthreads();  // B3: sattn complete; sout region (slice 1) writable

  // ---- OUT = attn @ Wo + bo -> sout (co-op, 2 n-tiles/wave) ----
  {
    bf16x8 aa[4];
#pragma unroll
    for (int kt = 0; kt < 4; ++kt)
      aa[kt] = *(const bf16x8*)(sattn + lr * ST + kt * 32 + lq * 8);
#pragma unroll
    for (int ni = 0; ni < 2; ++ni) {
      const int nt = wv * 2 + ni;
      f32x4 acc = {0.f, 0.f, 0.f, 0.f};
#pragma unroll
      for (int kt = 0; kt < 4; ++kt)
        acc = MFMA(aa[kt], wo[ni][kt], acc);
      const float bj = outb[nt * 16 + lr];
      f32x4 r;
      r[0] = acc[0] + bj; r[1] = acc[1] + bj;
      r[2] = acc[2] + bj; r[3] = acc[3] + bj;
      ctile_store(sout, lq * 4, nt * 16 + lr, r);
    }
  }
  // hoist X3's W2 B-frags across B4 (independent of sout)
  bf16x8 w2f[2][4];
#pragma unroll
  for (int nt = 0; nt < 2; ++nt) {
    const unsigned short* bp = wsb + OFF_W2 + (nt * 4) * 512 + ln * 8;
#pragma unroll
    for (int kt = 0; kt < 4; ++kt)
      w2f[nt][kt] = *(const bf16x8*)(bp + kt * 512);
  }
  __syncthreads();  // B4: sout complete

  // ---- X3 = out @ fc2 + b (redundant per wave), mask, row-sum ----
  {
    bf16x8 ao[4];
#pragma unroll
    for (int kt = 0; kt < 4; ++kt)
      ao[kt] = *(const bf16x8*)(sout + lr * ST + kt * 32 + lq * 8);
    f32x4 Cx[2];
#pragma unroll
    for (int nt = 0; nt < 2; ++nt) {
      f32x4 acc = {0.f, 0.f, 0.f, 0.f};
#pragma unroll
      for (int kt = 0; kt < 4; ++kt)
        acc = MFMA(ao[kt], w2f[nt][kt], acc);
      Cx[nt] = acc;
    }
    const float b0 = fc2b[lr], b1 = fc2b[16 + lr];
    float rs[4];
#pragma unroll
    for (int r = 0; r < 4; ++r) {
      const int row = lq * 4 + r;
      rs[r] = sm[row] ? 0.f : (Cx[0][r] + b0 + Cx[1][r] + b1);
    }
#pragma unroll
    for (int k = 1; k < 16; k <<= 1)
#pragma unroll
      for (int r = 0; r < 4; ++r) rs[r] += __shfl_xor(rs[r], k);
    if (wv == 0 && lr == 0) {
#pragma unroll
      for (int r = 0; r < 4; ++r) {
        const int q = lq * 4 + r;
        sres[q] = p ? rs[r] : fabsf(rs[r]) * (1.f / 32.f);
      }
    }
  }

  __syncthreads();
  if (t == 0) {
    float s = 0.f;
    if (p == 0) {
      const float* qs = agent_qs + (size_t)b * NA;
#pragma unroll
      for (int q = 0; q < NA; ++q) s += qs[q] * sres[q];
    } else {
#pragma unroll
      for (int q = 0; q < NA; ++q) s += sres[q];
      s *= (1.f / 512.f);
    }
    atomicAdd(out_g + b, s);  // out zeroed by harness memset; 2 addends/b
  }
}

extern "C" void kernel_launch(void* const* d_in, const int* in_sizes, int n_in,
                              void* d_out, int out_size, void* d_ws,
                              size_t ws_size, hipStream_t stream) {
  (void)n_in; (void)out_size; (void)ws_size;
  const int nb = in_sizes[0] / NA;  // BS*T = 1600
  unsigned short* wsw = (unsigned short*)d_ws;
  int* mflag = (int*)((char*)d_ws + WS_FLAG_OFF);

  hipLaunchKernelGGL(prep_kernel, dim3(81), dim3(256), 0, stream,
                     (const float*)d_in[3], (const float*)d_in[5],
                     (const float*)d_in[6], (const float*)d_in[8],
                     (const float*)d_in[10], (const float*)d_in[12],
                     (const float*)d_in[13], (const float*)d_in[15],
                     (const unsigned char*)d_in[2], wsw, mflag);
  hipLaunchKernelGGL(qmix_mfma, dim3(nb * 2), dim3(256), 0, stream,
                     (const float*)d_in[0], (const float*)d_in[1],
                     (const unsigned char*)d_in[2], (const unsigned short*)wsw,
                     (const int*)mflag, (const float*)d_in[4],
                     (const float*)d_in[7], (const float*)d_in[9],
                     (const float*)d_in[11], (const float*)d_in[14],
                     (const float*)d_in[16], (float*)d_out);
}